// Round 4
// baseline (907.160 us; speedup 1.0000x reference)
//
#include <hip/hip_runtime.h>

// ConvSA: B=8, C=256, H=W=48 (N=2304), E=512.
// out[b,e,i] = sum_j softmax_j(q[:,i].k[:,j]) * v[e,j] + v[e,i]
// Flash attention v5 (cross-jt software pipeline):
//  - Swapped QK^T (S = mfma(k,q), D col = i) -> lane-local softmax state.
//  - Merged region per jt: C(jt) (P.V from sP2+v-stream) INTERLEAVED with
//    A(jt+1) (k-stream + q-LDS) -> 64 contiguous MFMAs, 3 load streams,
//    zero barriers inside. 2 barriers/jt around the softmax only.
//  - Deferred-l: psum(t-1) read at SM(t) (add-then-rescale) so one
//    barrier-pair/jt suffices; sP2/pmax/psum double-buffered by jt&1.
//  - q_lds in frag-block layout (32 x 1KB linear blocks): conflict-free
//    ds_read_b128 with immediate offsets, no address math.
//  - alpha-rescale skipped when __all(mnew==m_reg) (defer-max).
//  - launch_bounds(256,3): target 3 blocks/CU (LDS 51.2 KB).

typedef _Float16 f16;
typedef _Float16 f16x4 __attribute__((ext_vector_type(4)));
typedef _Float16 f16x8 __attribute__((ext_vector_type(8)));
typedef float    f32x4  __attribute__((ext_vector_type(4)));
typedef float    f32x16 __attribute__((ext_vector_type(16)));

__device__ __forceinline__ f32x16 mfma16(f16x8 a, f16x8 b, f32x16 c) {
  return __builtin_amdgcn_mfma_f32_32x32x16_f16(a, b, c, 0, 0, 0);
}

#define NB   8
#define NC   256
#define NH   48
#define NN   2304     // 48*48
#define NE   512
#define HP   50       // padded H/W

// ---------------- pack kernels ----------------

// feat NCHW fp32 -> zero-padded NHWC [b][50][50][256] fp16
__global__ void pack_feat(const float* __restrict__ x, f16* __restrict__ p) {
  int idx = blockIdx.x * 256 + threadIdx.x;       // 8*50*50*256
  int c  = idx & 255;
  int q  = idx >> 8;
  int xp = q % 50; int t = q / 50; int yp = t % 50; int b = t / 50;
  float v = 0.f;
  if (yp >= 1 && yp <= 48 && xp >= 1 && xp <= 48)
    v = x[((b * NC + c) * NH + (yp - 1)) * NH + (xp - 1)];
  p[idx] = (f16)v;
}

// W OIHW [512][256][3][3] fp32 -> A-frag blocks:
// [cc 16][t 9][et 16] x (el 32 x cl 16) contiguous 512-f16 (1 KB) blocks.
__global__ void pack_w(const float* __restrict__ wq, const float* __restrict__ wk,
                       const float* __restrict__ wv,
                       f16* __restrict__ oq, f16* __restrict__ ok,
                       f16* __restrict__ ov) {
  int idx = blockIdx.x * 256 + threadIdx.x;       // 9*512*256
  int c = idx & 255;
  int r = idx >> 8;
  int e = r & 511; int t = r >> 9;
  int src = (e * NC + c) * 9 + t;
  int cc = c >> 4, cl = c & 15, et = e >> 5, el = e & 31;
  int dst = ((cc * 9 + t) * 16 + et) * 512 + el * 16 + cl;
  oq[dst] = (f16)wq[src];
  ok[dst] = (f16)wk[src];
  ov[dst] = (f16)wv[src];
}

// ---------------- fused implicit-GEMM conv3x3 for q,k,v ----------------
// Block 256 thr; out tile 32 e x 384 pos x {q,k,v}; grid (16 e-tiles, 48).
// q -> row-major [pos][e]; k -> k_f frag blocks [b][j/32][e/16][lane64][8];
// v -> v_f frag blocks [b][e/32][j/16][lane64][8].
__global__ __launch_bounds__(256, 2) void conv3_qkv(
    const f16* __restrict__ xh,
    const f16* __restrict__ wq, const f16* __restrict__ wk,
    const f16* __restrict__ wv,
    const float* __restrict__ bq, const float* __restrict__ bk,
    const float* __restrict__ bv,
    f16* __restrict__ oq, f16* __restrict__ kf, f16* __restrict__ vf) {
  __shared__ __align__(16) f16 sx[12000];         // 10*50*24

  const int tid = threadIdx.x;
  const int lane = tid & 63, wvx = tid >> 6;
  const int l31 = lane & 31;
  const int koff = (lane >> 5) * 8;
  const int et = blockIdx.x;
  const int e0 = et * 32;
  const int by = blockIdx.y;
  const int b = by / 6, strip = by % 6;
  const int y0 = strip * 8;

  int pb[3];
#pragma unroll
  for (int nt = 0; nt < 3; ++nt) {
    int n = wvx * 96 + nt * 32 + l31;
    pb[nt] = (n / 48) * 50 + (n % 48);
  }

  // staging coords: 4 chunks/thread
  int sgp[4], sgo[4]; bool sok[4]; int gbase[4];
#pragma unroll
  for (int u = 0; u < 4; ++u) {
    int g = u * 256 + tid;
    sok[u] = (g < 1000);
    int gg = sok[u] ? g : 999;
    sgp[u] = gg >> 1; sgo[u] = (gg & 1) * 8;
    int row = sgp[u] / 50, xx = sgp[u] % 50;
    gbase[u] = ((b * HP + y0 + row) * HP + xx) * NC + sgo[u];
  }

  f32x16 acc[3][3];                               // [qkv][nt]
#pragma unroll
  for (int f = 0; f < 3; ++f)
#pragma unroll
    for (int nt = 0; nt < 3; ++nt)
#pragma unroll
      for (int i = 0; i < 16; ++i) acc[f][nt][i] = 0.f;

  f16x8 rx[4];
#pragma unroll
  for (int u = 0; u < 4; ++u)
    rx[u] = *(const f16x8*)(xh + gbase[u]);       // cc=0 prefetch

  const int wlocal = l31 * 16 + koff;

  for (int cc = 0; cc < 16; ++cc) {
    __syncthreads();                              // prev compute done
#pragma unroll
    for (int u = 0; u < 4; ++u)
      if (sok[u]) *(f16x8*)(sx + sgp[u] * 24 + sgo[u]) = rx[u];
    __syncthreads();
    if (cc < 15) {                                // overlap next loads w/ compute
      int c0 = (cc + 1) * 16;
#pragma unroll
      for (int u = 0; u < 4; ++u)
        rx[u] = *(const f16x8*)(xh + gbase[u] + c0);
    }
#pragma unroll
    for (int t = 0; t < 9; ++t) {
      const int dy = t / 3, dx = t % 3;
      const int dpo = (dy * 50 + dx) * 24 + koff;
      f16x8 bh[3];
#pragma unroll
      for (int nt = 0; nt < 3; ++nt)
        bh[nt] = *(const f16x8*)(sx + pb[nt] * 24 + dpo);
      int wb = ((cc * 9 + t) * 16 + et) * 512 + wlocal;
      f16x8 aq = *(const f16x8*)(wq + wb);
      f16x8 ak = *(const f16x8*)(wk + wb);
      f16x8 av = *(const f16x8*)(wv + wb);
#pragma unroll
      for (int nt = 0; nt < 3; ++nt) {
        acc[0][nt] = mfma16(aq, bh[nt], acc[0][nt]);
        acc[1][nt] = mfma16(ak, bh[nt], acc[1][nt]);
        acc[2][nt] = mfma16(av, bh[nt], acc[2][nt]);
      }
    }
  }

  // epilogue: C/D layout col=lane&31 (=pos), row=(r&3)+8*(r>>2)+4*(lane>>5) (=e)
  const int colh = (lane >> 5) * 4;
#pragma unroll
  for (int nt = 0; nt < 3; ++nt) {
    int n = wvx * 96 + nt * 32 + l31;
    int pos = (y0 + n / 48) * 48 + (n % 48);
    const int jblk = pos >> 5, jl = pos & 31;
    const int jc = pos >> 4, lhv = (pos >> 3) & 1, uv = pos & 7;
#pragma unroll
    for (int g = 0; g < 4; ++g) {
      int eb = e0 + g * 8 + colh;
      f32x4 sq = *(const f32x4*)(bq + eb);
      f32x4 sk = *(const f32x4*)(bk + eb);
      f32x4 sv = *(const f32x4*)(bv + eb);
      f16x4 hq, hk;
#pragma unroll
      for (int j = 0; j < 4; ++j) {
        hq[j] = (f16)(acc[0][nt][g * 4 + j] + sq[j]);
        hk[j] = (f16)(acc[1][nt][g * 4 + j] + sk[j]);
        int e = eb + j;
        // v_f: [b][e>>5][pos>>4][((pos>>3)&1)*32 + (e&31)][pos&7]
        vf[((((size_t)b * 16 + (e >> 5)) * 144 + jc) * 64 + lhv * 32 + (e & 31)) * 8 + uv] =
            (f16)(acc[2][nt][g * 4 + j] + sv[j]);
      }
      // k_f: [b][pos>>5][eb>>4][((eb>>3)&1)*32 + (pos&31)][eb&7 .. +3]
      *(f16x4*)(kf + ((((size_t)b * 72 + jblk) * 32 + (eb >> 4)) * 64 +
                      ((eb >> 3) & 1) * 32 + jl) * 8 + (eb & 7)) = hk;
      *(f16x4*)(oq + ((size_t)b * NN + pos) * NE + eb) = hq;
    }
  }
}

// ---------------- flash attention v5 ----------------
__global__ __launch_bounds__(256, 3) void attn(
    const f16* __restrict__ qt, const f16* __restrict__ kf,
    const f16* __restrict__ vf, float* __restrict__ out) {
  __shared__ __align__(16) f16 q_lds[16384];      // 32 frag blocks x 512 f16 = 32 KB
  __shared__ __align__(16) f16 sP2[8192];         // dbuf 2 x (8 chunks x 64 x 8) = 16 KB
  __shared__ __align__(16) float s_pmax[256];     // dbuf 2 x (32 i x 4 w)
  __shared__ __align__(16) float s_psum[256];

  const int tid = threadIdx.x;
  const int lane = tid & 63, wvx = tid >> 6;
  const int l31 = lane & 31, lh = lane >> 5;
  const int bid = blockIdx.x;
  const int b = bid & 7;
  const int i0 = (bid >> 3) * 32;

  // ---- stage q tile (32 x 512) once, into frag-block layout ----
  {
    const f16* qb = qt + ((size_t)b * NN + i0) * NE;
#pragma unroll
    for (int it = 0; it < 8; ++it) {
      int g = it * 256 + tid;
      int row = g >> 6, gr = g & 63;
      f16x8 v = *(const f16x8*)(qb + row * NE + gr * 8);
      // frag block ec=gr>>1: lane' = (gr&1)*32 + row, inner = e&7
      *(f16x8*)(q_lds + (gr >> 1) * 512 + (gr & 1) * 256 + row * 8) = v;
    }
  }
  __syncthreads();

  float m_reg = -1e30f, l_reg = 0.f;
  f32x16 O[4];
#pragma unroll
  for (int nt = 0; nt < 4; ++nt)
#pragma unroll
    for (int i = 0; i < 16; ++i) O[nt][i] = 0.f;

  const f16* kfw = kf + (size_t)(b * 72 + wvx) * 16384 + lane * 8;
  const f16* vfw = vf + (size_t)(b * 16 + wvx * 4) * 73728 + lane * 8;
  const f16* qlw = q_lds + lane * 8;

  f32x16 S0, S1;
#pragma unroll
  for (int i = 0; i < 16; ++i) { S0[i] = 0.f; S1[i] = 0.f; }

  // ---- prologue: A(0) — S = k.q^T for jt=0 ----
  {
    const f16* kfl = kfw;
    f16x8 kp[3];
#pragma unroll
    for (int t = 0; t < 3; ++t) kp[t] = *(const f16x8*)(kfl + t * 512);
#pragma unroll
    for (int c = 0; c < 32; ++c) {
      f16x8 ak = kp[c % 3];
      if (c + 3 < 32) kp[c % 3] = *(const f16x8*)(kfl + (c + 3) * 512);
      f16x8 aq = *(const f16x8*)(qlw + c * 512);
      if (c & 1) S1 = mfma16(ak, aq, S1);
      else       S0 = mfma16(ak, aq, S0);
    }
  }

  for (int jt = 0; jt < 18; ++jt) {
    const int t = jt;
    // ---- wmax(t) from S0/S1 ----
    f32x16 S;
#pragma unroll
    for (int r = 0; r < 16; ++r) S[r] = S0[r] + S1[r];
    float wmax = S[0];
#pragma unroll
    for (int r = 1; r < 16; ++r) wmax = fmaxf(wmax, S[r]);
    wmax = fmaxf(wmax, __shfl_xor(wmax, 32, 64));
    if (lane < 32) s_pmax[(t & 1) * 128 + l31 * 4 + wvx] = wmax;
    __syncthreads();                              // barrier 1

    // ---- SM(t) ----
    f32x4 pm4 = *(const f32x4*)(s_pmax + (t & 1) * 128 + l31 * 4);
    float gmax = fmaxf(fmaxf(pm4[0], pm4[1]), fmaxf(pm4[2], pm4[3]));
    if (t > 0) {                                  // deferred l add for t-1
      f32x4 ps4 = *(const f32x4*)(s_psum + ((t - 1) & 1) * 128 + l31 * 4);
      l_reg += ps4[0] + ps4[1] + ps4[2] + ps4[3];
    }
    float mnew = fmaxf(m_reg, gmax);
    if (!__all(mnew == m_reg)) {                  // defer-max skip
      float alpha = __expf(m_reg - mnew);
      l_reg *= alpha;
      m_reg = mnew;
#pragma unroll
      for (int nt = 0; nt < 4; ++nt)
#pragma unroll
        for (int r = 0; r < 16; ++r) O[nt][r] *= alpha;
    }
    f16* spw = sP2 + (t & 1) * 4096;
    f16 ph[16];
    float psum = 0.f;
#pragma unroll
    for (int r = 0; r < 16; ++r) {
      f16 p = (f16)__expf(S[r] - mnew);
      ph[r] = p;
      psum += (float)p;
    }
    // pack quads -> B-frags via cross-half exchange, write sP2[t&1]
    union Q4 { f16x4 h; int i2[2]; };
    Q4 q4[4];
#pragma unroll
    for (int t4 = 0; t4 < 4; ++t4)
#pragma unroll
      for (int u = 0; u < 4; ++u) q4[t4].h[u] = ph[t4 * 4 + u];
#pragma unroll
    for (int ks = 0; ks < 2; ++ks) {
      Q4 t1, t2;
      t1.i2[0] = __shfl_xor(q4[2 * ks + 1].i2[0], 32, 64);
      t1.i2[1] = __shfl_xor(q4[2 * ks + 1].i2[1], 32, 64);
      t2.i2[0] = __shfl_xor(q4[2 * ks].i2[0], 32, 64);
      t2.i2[1] = __shfl_xor(q4[2 * ks].i2[1], 32, 64);
      f16x4 first  = lh ? t1.h : q4[2 * ks].h;
      f16x4 second = lh ? q4[2 * ks + 1].h : t2.h;
      f16x8 frag;
#pragma unroll
      for (int u = 0; u < 4; ++u) { frag[u] = first[u]; frag[4 + u] = second[u]; }
      *(f16x8*)(spw + ((wvx * 2 + ks) * 64 + lane) * 8) = frag;
    }
    psum += __shfl_xor(psum, 32, 64);
    if (lane < 32) s_psum[(t & 1) * 128 + l31 * 4 + wvx] = psum;
    __syncthreads();                              // barrier 2 (sP2+psum visible)

    // ---- merged region: C(t) ∥ A(t+1), zero barriers ----
    const f16* vfl = vfw + (size_t)t * 4096;
    const f16* spc = spw;
    if (jt < 17) {
      const f16* kfl = kfw + (size_t)(jt + 1) * 4 * 16384;
#pragma unroll
      for (int r = 0; r < 16; ++r) { S0[r] = 0.f; S1[r] = 0.f; }
      f16x8 kp[3], vp[3];
#pragma unroll
      for (int p = 0; p < 3; ++p) kp[p] = *(const f16x8*)(kfl + p * 512);
#pragma unroll
      for (int p = 0; p < 3; ++p)
        vp[p] = *(const f16x8*)(vfl + (size_t)(p & 3) * 73728 + (p >> 2) * 512);
      f16x8 ap0 = *(const f16x8*)(spc + lane * 8);
      f16x8 ap1 = *(const f16x8*)(spc + (64 + lane) * 8);
#pragma unroll
      for (int c = 0; c < 32; ++c) {
        f16x8 ak = kp[c % 3];
        if (c + 3 < 32) kp[c % 3] = *(const f16x8*)(kfl + (c + 3) * 512);
        f16x8 av = vp[c % 3];
        if (c + 3 < 32) {
          int c2 = c + 3;
          vp[c % 3] = *(const f16x8*)(vfl + (size_t)(c2 & 3) * 73728 + (c2 >> 2) * 512);
        }
        f16x8 aq = *(const f16x8*)(qlw + c * 512);
        if (c & 1) S1 = mfma16(ak, aq, S1);
        else       S0 = mfma16(ak, aq, S0);
        O[c & 3] = mfma16(av, ap0, O[c & 3]);
        if ((c & 3) == 3) {
          ap0 = ap1;
          if ((c >> 2) < 6) ap1 = *(const f16x8*)(spc + (((c >> 2) + 2) * 64 + lane) * 8);
        }
      }
    } else {
      // C(17) only
      f16x8 vp[3];
#pragma unroll
      for (int p = 0; p < 3; ++p)
        vp[p] = *(const f16x8*)(vfl + (size_t)(p & 3) * 73728 + (p >> 2) * 512);
      f16x8 ap0 = *(const f16x8*)(spc + lane * 8);
      f16x8 ap1 = *(const f16x8*)(spc + (64 + lane) * 8);
#pragma unroll
      for (int c = 0; c < 32; ++c) {
        f16x8 av = vp[c % 3];
        if (c + 3 < 32) {
          int c2 = c + 3;
          vp[c % 3] = *(const f16x8*)(vfl + (size_t)(c2 & 3) * 73728 + (c2 >> 2) * 512);
        }
        O[c & 3] = mfma16(av, ap0, O[c & 3]);
        if ((c & 3) == 3) {
          ap0 = ap1;
          if ((c >> 2) < 6) ap1 = *(const f16x8*)(spc + (((c >> 2) + 2) * 64 + lane) * 8);
        }
      }
    }
  }

  // ---- epilogue: finish l (psum(17) already visible), normalize, residual ----
  {
    f32x4 ps4 = *(const f32x4*)(s_psum + 128 + l31 * 4);   // (17&1)=1
    l_reg += ps4[0] + ps4[1] + ps4[2] + ps4[3];
  }
  float inv = 1.0f / l_reg;
  const int ii = i0 + l31;
  const int jcR = ii >> 4, lhR = (ii >> 3) & 1, uR = ii & 7;
#pragma unroll
  for (int nt = 0; nt < 4; ++nt) {
    const f16* vres = vf + ((((size_t)(b * 16 + wvx * 4 + nt)) * 144 + jcR) * 64 + lhR * 32) * 8 + uR;
    const int ebase = wvx * 128 + nt * 32;
#pragma unroll
    for (int r = 0; r < 16; ++r) {
      int el = (r & 3) + 8 * (r >> 2) + 4 * lh;
      float rv = (float)vres[el * 8];
      out[((size_t)b * NE + ebase + el) * NN + ii] = O[nt][r] * inv + rv;
    }
  }
}

// ---------------- launch ----------------
extern "C" void kernel_launch(void* const* d_in, const int* in_sizes, int n_in,
                              void* d_out, int out_size, void* d_ws, size_t ws_size,
                              hipStream_t stream) {
  const float* feat = (const float*)d_in[0];
  const float* Wq = (const float*)d_in[1];
  const float* bq = (const float*)d_in[2];
  const float* Wk = (const float*)d_in[3];
  const float* bk = (const float*)d_in[4];
  const float* Wv = (const float*)d_in[5];
  const float* bv = (const float*)d_in[6];
  float* out = (float*)d_out;

  char* ws = (char*)d_ws;
  size_t off = 0;
  auto alloc = [&](size_t bytes) {
    void* p = ws + off;
    off += (bytes + 255) & ~(size_t)255;
    return p;
  };
  const size_t FP = (size_t)NB * HP * HP * NC;     // 5,120,000
  const size_t WP = (size_t)9 * NE * NC;           // 1,179,648
  const size_t QP = (size_t)NB * NN * NE;          // 9,437,184
  f16* fp  = (f16*)alloc(FP * 2);
  f16* wq  = (f16*)alloc(WP * 2);
  f16* wk  = (f16*)alloc(WP * 2);
  f16* wv  = (f16*)alloc(WP * 2);
  f16* q_t = (f16*)alloc(QP * 2);
  f16* k_f = (f16*)alloc(QP * 2);
  f16* v_f = (f16*)alloc(QP * 2);

  pack_feat<<<dim3(FP / 256), dim3(256), 0, stream>>>(feat, fp);
  pack_w<<<dim3(WP / 256), dim3(256), 0, stream>>>(Wq, Wk, Wv, wq, wk, wv);

  conv3_qkv<<<dim3(16, 48), dim3(256), 0, stream>>>(
      fp, wq, wk, wv, bq, bk, bv, q_t, k_f, v_f);

  attn<<<dim3(576), dim3(256), 0, stream>>>(q_t, k_f, v_f, out);
}

// Round 6
// 806.399 us; speedup vs baseline: 1.1250x; 1.1250x over previous
//
#include <hip/hip_runtime.h>

// ConvSA: B=8, C=256, H=W=48 (N=2304), E=512.
// out[b,e,i] = sum_j softmax_j(q[:,i].k[:,j]) * v[e,j] + v[e,i]
// Flash attention v5b (cross-jt software pipeline, spill-free):
//  - Swapped QK^T (S = mfma(k,q), D col = i) -> lane-local softmax state.
//  - Merged region per jt: C(jt) (P.V from sP2+v-stream) INTERLEAVED with
//    A(jt+1) (k-stream + q-LDS) -> 64 contiguous MFMAs, 3 load streams,
//    zero barriers inside. 2 barriers/jt around the softmax only.
//  - launch_bounds(256,2): merged region keeps S0/S1(32)+O(64) acc live;
//    the (256,3) cap in R4 forced accumulator spills (1.37 GB scratch
//    writes/dispatch). Occupancy is grid-limited at 2.25 blocks/CU anyway
//    (576 blocks / 256 CU), so the relaxed bound costs nothing.
//  - Deferred-l: psum(t-1) read at SM(t); sP2/pmax/psum double-buffered.
//  - q_lds in frag-block layout (32 x 1KB linear blocks): conflict-free
//    ds_read_b128, immediate offsets.
//  - alpha-rescale skipped when __all(mnew==m_reg) (defer-max).
// (R5 resubmission: R5 bench was an infra failure — container acquisition —
//  not a kernel result; source identical to the R5 submission.)

typedef _Float16 f16;
typedef _Float16 f16x4 __attribute__((ext_vector_type(4)));
typedef _Float16 f16x8 __attribute__((ext_vector_type(8)));
typedef float    f32x4  __attribute__((ext_vector_type(4)));
typedef float    f32x16 __attribute__((ext_vector_type(16)));

__device__ __forceinline__ f32x16 mfma16(f16x8 a, f16x8 b, f32x16 c) {
  return __builtin_amdgcn_mfma_f32_32x32x16_f16(a, b, c, 0, 0, 0);
}

#define NB   8
#define NC   256
#define NH   48
#define NN   2304     // 48*48
#define NE   512
#define HP   50       // padded H/W

// ---------------- pack kernels ----------------

// feat NCHW fp32 -> zero-padded NHWC [b][50][50][256] fp16
__global__ void pack_feat(const float* __restrict__ x, f16* __restrict__ p) {
  int idx = blockIdx.x * 256 + threadIdx.x;       // 8*50*50*256
  int c  = idx & 255;
  int q  = idx >> 8;
  int xp = q % 50; int t = q / 50; int yp = t % 50; int b = t / 50;
  float v = 0.f;
  if (yp >= 1 && yp <= 48 && xp >= 1 && xp <= 48)
    v = x[((b * NC + c) * NH + (yp - 1)) * NH + (xp - 1)];
  p[idx] = (f16)v;
}

// W OIHW [512][256][3][3] fp32 -> A-frag blocks:
// [cc 16][t 9][et 16] x (el 32 x cl 16) contiguous 512-f16 (1 KB) blocks.
__global__ void pack_w(const float* __restrict__ wq, const float* __restrict__ wk,
                       const float* __restrict__ wv,
                       f16* __restrict__ oq, f16* __restrict__ ok,
                       f16* __restrict__ ov) {
  int idx = blockIdx.x * 256 + threadIdx.x;       // 9*512*256
  int c = idx & 255;
  int r = idx >> 8;
  int e = r & 511; int t = r >> 9;
  int src = (e * NC + c) * 9 + t;
  int cc = c >> 4, cl = c & 15, et = e >> 5, el = e & 31;
  int dst = ((cc * 9 + t) * 16 + et) * 512 + el * 16 + cl;
  oq[dst] = (f16)wq[src];
  ok[dst] = (f16)wk[src];
  ov[dst] = (f16)wv[src];
}

// ---------------- fused implicit-GEMM conv3x3 for q,k,v ----------------
// Block 256 thr; out tile 32 e x 384 pos x {q,k,v}; grid (16 e-tiles, 48).
// q -> row-major [pos][e]; k -> k_f frag blocks [b][j/32][e/16][lane64][8];
// v -> v_f frag blocks [b][e/32][j/16][lane64][8].
__global__ __launch_bounds__(256, 2) void conv3_qkv(
    const f16* __restrict__ xh,
    const f16* __restrict__ wq, const f16* __restrict__ wk,
    const f16* __restrict__ wv,
    const float* __restrict__ bq, const float* __restrict__ bk,
    const float* __restrict__ bv,
    f16* __restrict__ oq, f16* __restrict__ kf, f16* __restrict__ vf) {
  __shared__ __align__(16) f16 sx[12000];         // 10*50*24

  const int tid = threadIdx.x;
  const int lane = tid & 63, wvx = tid >> 6;
  const int l31 = lane & 31;
  const int koff = (lane >> 5) * 8;
  const int et = blockIdx.x;
  const int e0 = et * 32;
  const int by = blockIdx.y;
  const int b = by / 6, strip = by % 6;
  const int y0 = strip * 8;

  int pb[3];
#pragma unroll
  for (int nt = 0; nt < 3; ++nt) {
    int n = wvx * 96 + nt * 32 + l31;
    pb[nt] = (n / 48) * 50 + (n % 48);
  }

  // staging coords: 4 chunks/thread
  int sgp[4], sgo[4]; bool sok[4]; int gbase[4];
#pragma unroll
  for (int u = 0; u < 4; ++u) {
    int g = u * 256 + tid;
    sok[u] = (g < 1000);
    int gg = sok[u] ? g : 999;
    sgp[u] = gg >> 1; sgo[u] = (gg & 1) * 8;
    int row = sgp[u] / 50, xx = sgp[u] % 50;
    gbase[u] = ((b * HP + y0 + row) * HP + xx) * NC + sgo[u];
  }

  f32x16 acc[3][3];                               // [qkv][nt]
#pragma unroll
  for (int f = 0; f < 3; ++f)
#pragma unroll
    for (int nt = 0; nt < 3; ++nt)
#pragma unroll
      for (int i = 0; i < 16; ++i) acc[f][nt][i] = 0.f;

  f16x8 rx[4];
#pragma unroll
  for (int u = 0; u < 4; ++u)
    rx[u] = *(const f16x8*)(xh + gbase[u]);       // cc=0 prefetch

  const int wlocal = l31 * 16 + koff;

  for (int cc = 0; cc < 16; ++cc) {
    __syncthreads();                              // prev compute done
#pragma unroll
    for (int u = 0; u < 4; ++u)
      if (sok[u]) *(f16x8*)(sx + sgp[u] * 24 + sgo[u]) = rx[u];
    __syncthreads();
    if (cc < 15) {                                // overlap next loads w/ compute
      int c0 = (cc + 1) * 16;
#pragma unroll
      for (int u = 0; u < 4; ++u)
        rx[u] = *(const f16x8*)(xh + gbase[u] + c0);
    }
#pragma unroll
    for (int t = 0; t < 9; ++t) {
      const int dy = t / 3, dx = t % 3;
      const int dpo = (dy * 50 + dx) * 24 + koff;
      f16x8 bh[3];
#pragma unroll
      for (int nt = 0; nt < 3; ++nt)
        bh[nt] = *(const f16x8*)(sx + pb[nt] * 24 + dpo);
      int wb = ((cc * 9 + t) * 16 + et) * 512 + wlocal;
      f16x8 aq = *(const f16x8*)(wq + wb);
      f16x8 ak = *(const f16x8*)(wk + wb);
      f16x8 av = *(const f16x8*)(wv + wb);
#pragma unroll
      for (int nt = 0; nt < 3; ++nt) {
        acc[0][nt] = mfma16(aq, bh[nt], acc[0][nt]);
        acc[1][nt] = mfma16(ak, bh[nt], acc[1][nt]);
        acc[2][nt] = mfma16(av, bh[nt], acc[2][nt]);
      }
    }
  }

  // epilogue: C/D layout col=lane&31 (=pos), row=(r&3)+8*(r>>2)+4*(lane>>5) (=e)
  const int colh = (lane >> 5) * 4;
#pragma unroll
  for (int nt = 0; nt < 3; ++nt) {
    int n = wvx * 96 + nt * 32 + l31;
    int pos = (y0 + n / 48) * 48 + (n % 48);
    const int jblk = pos >> 5, jl = pos & 31;
    const int jc = pos >> 4, lhv = (pos >> 3) & 1, uv = pos & 7;
#pragma unroll
    for (int g = 0; g < 4; ++g) {
      int eb = e0 + g * 8 + colh;
      f32x4 sq = *(const f32x4*)(bq + eb);
      f32x4 sk = *(const f32x4*)(bk + eb);
      f32x4 sv = *(const f32x4*)(bv + eb);
      f16x4 hq, hk;
#pragma unroll
      for (int j = 0; j < 4; ++j) {
        hq[j] = (f16)(acc[0][nt][g * 4 + j] + sq[j]);
        hk[j] = (f16)(acc[1][nt][g * 4 + j] + sk[j]);
        int e = eb + j;
        // v_f: [b][e>>5][pos>>4][((pos>>3)&1)*32 + (e&31)][pos&7]
        vf[((((size_t)b * 16 + (e >> 5)) * 144 + jc) * 64 + lhv * 32 + (e & 31)) * 8 + uv] =
            (f16)(acc[2][nt][g * 4 + j] + sv[j]);
      }
      // k_f: [b][pos>>5][eb>>4][((eb>>3)&1)*32 + (pos&31)][eb&7 .. +3]
      *(f16x4*)(kf + ((((size_t)b * 72 + jblk) * 32 + (eb >> 4)) * 64 +
                      ((eb >> 3) & 1) * 32 + jl) * 8 + (eb & 7)) = hk;
      *(f16x4*)(oq + ((size_t)b * NN + pos) * NE + eb) = hq;
    }
  }
}

// ---------------- flash attention v5b ----------------
__global__ __launch_bounds__(256, 2) void attn(
    const f16* __restrict__ qt, const f16* __restrict__ kf,
    const f16* __restrict__ vf, float* __restrict__ out) {
  __shared__ __align__(16) f16 q_lds[16384];      // 32 frag blocks x 512 f16 = 32 KB
  __shared__ __align__(16) f16 sP2[8192];         // dbuf 2 x (8 chunks x 64 x 8) = 16 KB
  __shared__ __align__(16) float s_pmax[256];     // dbuf 2 x (32 i x 4 w)
  __shared__ __align__(16) float s_psum[256];

  const int tid = threadIdx.x;
  const int lane = tid & 63, wvx = tid >> 6;
  const int l31 = lane & 31, lh = lane >> 5;
  const int bid = blockIdx.x;
  const int b = bid & 7;
  const int i0 = (bid >> 3) * 32;

  // ---- stage q tile (32 x 512) once, into frag-block layout ----
  {
    const f16* qb = qt + ((size_t)b * NN + i0) * NE;
#pragma unroll
    for (int it = 0; it < 8; ++it) {
      int g = it * 256 + tid;
      int row = g >> 6, gr = g & 63;
      f16x8 v = *(const f16x8*)(qb + row * NE + gr * 8);
      // frag block ec=gr>>1: lane' = (gr&1)*32 + row, inner = e&7
      *(f16x8*)(q_lds + (gr >> 1) * 512 + (gr & 1) * 256 + row * 8) = v;
    }
  }
  __syncthreads();

  float m_reg = -1e30f, l_reg = 0.f;
  f32x16 O[4];
#pragma unroll
  for (int nt = 0; nt < 4; ++nt)
#pragma unroll
    for (int i = 0; i < 16; ++i) O[nt][i] = 0.f;

  const f16* kfw = kf + (size_t)(b * 72 + wvx) * 16384 + lane * 8;
  const f16* vfw = vf + (size_t)(b * 16 + wvx * 4) * 73728 + lane * 8;
  const f16* qlw = q_lds + lane * 8;

  f32x16 S0, S1;
#pragma unroll
  for (int i = 0; i < 16; ++i) { S0[i] = 0.f; S1[i] = 0.f; }

  // ---- prologue: A(0) — S = k.q^T for jt=0 ----
  {
    const f16* kfl = kfw;
    f16x8 kp[3];
#pragma unroll
    for (int t = 0; t < 3; ++t) kp[t] = *(const f16x8*)(kfl + t * 512);
#pragma unroll
    for (int c = 0; c < 32; ++c) {
      f16x8 ak = kp[c % 3];
      if (c + 3 < 32) kp[c % 3] = *(const f16x8*)(kfl + (c + 3) * 512);
      f16x8 aq = *(const f16x8*)(qlw + c * 512);
      if (c & 1) S1 = mfma16(ak, aq, S1);
      else       S0 = mfma16(ak, aq, S0);
    }
  }

  for (int jt = 0; jt < 18; ++jt) {
    const int t = jt;
    // ---- wmax(t) from S0/S1 ----
    f32x16 S;
#pragma unroll
    for (int r = 0; r < 16; ++r) S[r] = S0[r] + S1[r];
    float wmax = S[0];
#pragma unroll
    for (int r = 1; r < 16; ++r) wmax = fmaxf(wmax, S[r]);
    wmax = fmaxf(wmax, __shfl_xor(wmax, 32, 64));
    if (lane < 32) s_pmax[(t & 1) * 128 + l31 * 4 + wvx] = wmax;
    __syncthreads();                              // barrier 1

    // ---- SM(t) ----
    f32x4 pm4 = *(const f32x4*)(s_pmax + (t & 1) * 128 + l31 * 4);
    float gmax = fmaxf(fmaxf(pm4[0], pm4[1]), fmaxf(pm4[2], pm4[3]));
    if (t > 0) {                                  // deferred l add for t-1
      f32x4 ps4 = *(const f32x4*)(s_psum + ((t - 1) & 1) * 128 + l31 * 4);
      l_reg += ps4[0] + ps4[1] + ps4[2] + ps4[3];
    }
    float mnew = fmaxf(m_reg, gmax);
    if (!__all(mnew == m_reg)) {                  // defer-max skip
      float alpha = __expf(m_reg - mnew);
      l_reg *= alpha;
      m_reg = mnew;
#pragma unroll
      for (int nt = 0; nt < 4; ++nt)
#pragma unroll
        for (int r = 0; r < 16; ++r) O[nt][r] *= alpha;
    }
    f16* spw = sP2 + (t & 1) * 4096;
    f16 ph[16];
    float psum = 0.f;
#pragma unroll
    for (int r = 0; r < 16; ++r) {
      f16 p = (f16)__expf(S[r] - mnew);
      ph[r] = p;
      psum += (float)p;
    }
    // pack quads -> B-frags via cross-half exchange, write sP2[t&1]
    union Q4 { f16x4 h; int i2[2]; };
    Q4 q4[4];
#pragma unroll
    for (int t4 = 0; t4 < 4; ++t4)
#pragma unroll
      for (int u = 0; u < 4; ++u) q4[t4].h[u] = ph[t4 * 4 + u];
#pragma unroll
    for (int ks = 0; ks < 2; ++ks) {
      Q4 t1, t2;
      t1.i2[0] = __shfl_xor(q4[2 * ks + 1].i2[0], 32, 64);
      t1.i2[1] = __shfl_xor(q4[2 * ks + 1].i2[1], 32, 64);
      t2.i2[0] = __shfl_xor(q4[2 * ks].i2[0], 32, 64);
      t2.i2[1] = __shfl_xor(q4[2 * ks].i2[1], 32, 64);
      f16x4 first  = lh ? t1.h : q4[2 * ks].h;
      f16x4 second = lh ? q4[2 * ks + 1].h : t2.h;
      f16x8 frag;
#pragma unroll
      for (int u = 0; u < 4; ++u) { frag[u] = first[u]; frag[4 + u] = second[u]; }
      *(f16x8*)(spw + ((wvx * 2 + ks) * 64 + lane) * 8) = frag;
    }
    psum += __shfl_xor(psum, 32, 64);
    if (lane < 32) s_psum[(t & 1) * 128 + l31 * 4 + wvx] = psum;
    __syncthreads();                              // barrier 2 (sP2+psum visible)

    // ---- merged region: C(t) ∥ A(t+1), zero barriers ----
    const f16* vfl = vfw + (size_t)t * 4096;
    const f16* spc = spw;
    if (jt < 17) {
      const f16* kfl = kfw + (size_t)(jt + 1) * 4 * 16384;
#pragma unroll
      for (int r = 0; r < 16; ++r) { S0[r] = 0.f; S1[r] = 0.f; }
      f16x8 kp[3], vp[3];
#pragma unroll
      for (int p = 0; p < 3; ++p) kp[p] = *(const f16x8*)(kfl + p * 512);
#pragma unroll
      for (int p = 0; p < 3; ++p)
        vp[p] = *(const f16x8*)(vfl + (size_t)(p & 3) * 73728 + (p >> 2) * 512);
      f16x8 ap0 = *(const f16x8*)(spc + lane * 8);
      f16x8 ap1 = *(const f16x8*)(spc + (64 + lane) * 8);
#pragma unroll
      for (int c = 0; c < 32; ++c) {
        f16x8 ak = kp[c % 3];
        if (c + 3 < 32) kp[c % 3] = *(const f16x8*)(kfl + (c + 3) * 512);
        f16x8 av = vp[c % 3];
        if (c + 3 < 32) {
          int c2 = c + 3;
          vp[c % 3] = *(const f16x8*)(vfl + (size_t)(c2 & 3) * 73728 + (c2 >> 2) * 512);
        }
        f16x8 aq = *(const f16x8*)(qlw + c * 512);
        if (c & 1) S1 = mfma16(ak, aq, S1);
        else       S0 = mfma16(ak, aq, S0);
        O[c & 3] = mfma16(av, ap0, O[c & 3]);
        if ((c & 3) == 3) {
          ap0 = ap1;
          if ((c >> 2) < 6) ap1 = *(const f16x8*)(spc + (((c >> 2) + 2) * 64 + lane) * 8);
        }
      }
    } else {
      // C(17) only
      f16x8 vp[3];
#pragma unroll
      for (int p = 0; p < 3; ++p)
        vp[p] = *(const f16x8*)(vfl + (size_t)(p & 3) * 73728 + (p >> 2) * 512);
      f16x8 ap0 = *(const f16x8*)(spc + lane * 8);
      f16x8 ap1 = *(const f16x8*)(spc + (64 + lane) * 8);
#pragma unroll
      for (int c = 0; c < 32; ++c) {
        f16x8 av = vp[c % 3];
        if (c + 3 < 32) {
          int c2 = c + 3;
          vp[c % 3] = *(const f16x8*)(vfl + (size_t)(c2 & 3) * 73728 + (c2 >> 2) * 512);
        }
        O[c & 3] = mfma16(av, ap0, O[c & 3]);
        if ((c & 3) == 3) {
          ap0 = ap1;
          if ((c >> 2) < 6) ap1 = *(const f16x8*)(spc + (((c >> 2) + 2) * 64 + lane) * 8);
        }
      }
    }
  }

  // ---- epilogue: finish l (psum(17) already visible), normalize, residual ----
  {
    f32x4 ps4 = *(const f32x4*)(s_psum + 128 + l31 * 4);   // (17&1)=1
    l_reg += ps4[0] + ps4[1] + ps4[2] + ps4[3];
  }
  float inv = 1.0f / l_reg;
  const int ii = i0 + l31;
  const int jcR = ii >> 4, lhR = (ii >> 3) & 1, uR = ii & 7;
#pragma unroll
  for (int nt = 0; nt < 4; ++nt) {
    const f16* vres = vf + ((((size_t)(b * 16 + wvx * 4 + nt)) * 144 + jcR) * 64 + lhR * 32) * 8 + uR;
    const int ebase = wvx * 128 + nt * 32;
#pragma unroll
    for (int r = 0; r < 16; ++r) {
      int el = (r & 3) + 8 * (r >> 2) + 4 * lh;
      float rv = (float)vres[el * 8];
      out[((size_t)b * NE + ebase + el) * NN + ii] = O[nt][r] * inv + rv;
    }
  }
}

// ---------------- launch ----------------
extern "C" void kernel_launch(void* const* d_in, const int* in_sizes, int n_in,
                              void* d_out, int out_size, void* d_ws, size_t ws_size,
                              hipStream_t stream) {
  const float* feat = (const float*)d_in[0];
  const float* Wq = (const float*)d_in[1];
  const float* bq = (const float*)d_in[2];
  const float* Wk = (const float*)d_in[3];
  const float* bk = (const float*)d_in[4];
  const float* Wv = (const float*)d_in[5];
  const float* bv = (const float*)d_in[6];
  float* out = (float*)d_out;

  char* ws = (char*)d_ws;
  size_t off = 0;
  auto alloc = [&](size_t bytes) {
    void* p = ws + off;
    off += (bytes + 255) & ~(size_t)255;
    return p;
  };
  const size_t FP = (size_t)NB * HP * HP * NC;     // 5,120,000
  const size_t WP = (size_t)9 * NE * NC;           // 1,179,648
  const size_t QP = (size_t)NB * NN * NE;          // 9,437,184
  f16* fp  = (f16*)alloc(FP * 2);
  f16* wq  = (f16*)alloc(WP * 2);
  f16* wk  = (f16*)alloc(WP * 2);
  f16* wv  = (f16*)alloc(WP * 2);
  f16* q_t = (f16*)alloc(QP * 2);
  f16* k_f = (f16*)alloc(QP * 2);
  f16* v_f = (f16*)alloc(QP * 2);

  pack_feat<<<dim3(FP / 256), dim3(256), 0, stream>>>(feat, fp);
  pack_w<<<dim3(WP / 256), dim3(256), 0, stream>>>(Wq, Wk, Wv, wq, wk, wv);

  conv3_qkv<<<dim3(16, 48), dim3(256), 0, stream>>>(
      fp, wq, wk, wv, bq, bk, bv, q_t, k_f, v_f);

  attn<<<dim3(576), dim3(256), 0, stream>>>(q_t, k_f, v_f, out);
}

// Round 7
// 456.025 us; speedup vs baseline: 1.9893x; 1.7683x over previous
//
#include <hip/hip_runtime.h>

// ConvSA: B=8, C=256, H=W=48 (N=2304), E=512.
// out[b,e,i] = sum_j softmax_j(q[:,i].k[:,j]) * v[e,j] + v[e,i]
// R7 = R3-verified attn (v4, 182 us) + conv split into 3 single-output
// kernels (q/k/v):
//  - fused conv's acc[3][3] = 144 acc regs capped it at 8 waves/CU with a
//    1.5-round tail (768 blocks @ 2/CU). Split: acc[3] = 48 acc regs,
//    launch_bounds(256,3) -> 12 waves/CU, 768 blocks = 3/CU ALL resident.
//  - W-fragment loads get a 2-deep register pipe (load-use distance ~1 t-iter).
//  - attn v4: swapped QK^T (lane-local softmax), k/v streamed from global
//    frag blocks (depth-6 reg pipes), q persistent in LDS, 2 barriers/jt.

typedef _Float16 f16;
typedef _Float16 f16x4 __attribute__((ext_vector_type(4)));
typedef _Float16 f16x8 __attribute__((ext_vector_type(8)));
typedef float    f32x4  __attribute__((ext_vector_type(4)));
typedef float    f32x16 __attribute__((ext_vector_type(16)));

__device__ __forceinline__ f32x16 mfma16(f16x8 a, f16x8 b, f32x16 c) {
  return __builtin_amdgcn_mfma_f32_32x32x16_f16(a, b, c, 0, 0, 0);
}

#define NB   8
#define NC   256
#define NH   48
#define NN   2304     // 48*48
#define NE   512
#define HP   50       // padded H/W
#define QSTR 528      // q_lds row stride (f16), padded

// ---------------- pack kernels ----------------

// feat NCHW fp32 -> zero-padded NHWC [b][50][50][256] fp16
__global__ void pack_feat(const float* __restrict__ x, f16* __restrict__ p) {
  int idx = blockIdx.x * 256 + threadIdx.x;       // 8*50*50*256
  int c  = idx & 255;
  int q  = idx >> 8;
  int xp = q % 50; int t = q / 50; int yp = t % 50; int b = t / 50;
  float v = 0.f;
  if (yp >= 1 && yp <= 48 && xp >= 1 && xp <= 48)
    v = x[((b * NC + c) * NH + (yp - 1)) * NH + (xp - 1)];
  p[idx] = (f16)v;
}

// W OIHW [512][256][3][3] fp32 -> A-frag blocks:
// [cc 16][t 9][et 16] x (el 32 x cl 16) contiguous 512-f16 (1 KB) blocks.
__global__ void pack_w(const float* __restrict__ wq, const float* __restrict__ wk,
                       const float* __restrict__ wv,
                       f16* __restrict__ oq, f16* __restrict__ ok,
                       f16* __restrict__ ov) {
  int idx = blockIdx.x * 256 + threadIdx.x;       // 9*512*256
  int c = idx & 255;
  int r = idx >> 8;
  int e = r & 511; int t = r >> 9;
  int src = (e * NC + c) * 9 + t;
  int cc = c >> 4, cl = c & 15, et = e >> 5, el = e & 31;
  int dst = ((cc * 9 + t) * 16 + et) * 512 + el * 16 + cl;
  oq[dst] = (f16)wq[src];
  ok[dst] = (f16)wk[src];
  ov[dst] = (f16)wv[src];
}

// ---------------- implicit-GEMM conv3x3, ONE output per kernel ----------------
// Block 256 thr; out tile 32 e x 384 pos; grid (16 e-tiles, 48) = 768 blocks
// = exactly 3 blocks/CU, all resident. acc[3] = 48 acc regs -> 12 waves/CU.
// F=0: q row-major [b][pos][e]; F=1: k_f frag blocks; F=2: v_f frag blocks.
template<int F>
__global__ __launch_bounds__(256, 3) void conv3_one(
    const f16* __restrict__ xh, const f16* __restrict__ w,
    const float* __restrict__ bias, f16* __restrict__ o) {
  __shared__ __align__(16) f16 sx[12000];         // 10*50*24

  const int tid = threadIdx.x;
  const int lane = tid & 63, wvx = tid >> 6;
  const int l31 = lane & 31;
  const int koff = (lane >> 5) * 8;
  const int et = blockIdx.x;
  const int e0 = et * 32;
  const int by = blockIdx.y;
  const int b = by / 6, strip = by % 6;
  const int y0 = strip * 8;

  int pb[3];
#pragma unroll
  for (int nt = 0; nt < 3; ++nt) {
    int n = wvx * 96 + nt * 32 + l31;
    pb[nt] = (n / 48) * 50 + (n % 48);
  }

  // staging coords: 4 chunks/thread
  int sgp[4], sgo[4]; bool sok[4]; int gbase[4];
#pragma unroll
  for (int u = 0; u < 4; ++u) {
    int g = u * 256 + tid;
    sok[u] = (g < 1000);
    int gg = sok[u] ? g : 999;
    sgp[u] = gg >> 1; sgo[u] = (gg & 1) * 8;
    int row = sgp[u] / 50, xx = sgp[u] % 50;
    gbase[u] = ((b * HP + y0 + row) * HP + xx) * NC + sgo[u];
  }

  f32x16 acc[3];
#pragma unroll
  for (int nt = 0; nt < 3; ++nt)
#pragma unroll
    for (int i = 0; i < 16; ++i) acc[nt][i] = 0.f;

  f16x8 rx[4];
#pragma unroll
  for (int u = 0; u < 4; ++u)
    rx[u] = *(const f16x8*)(xh + gbase[u]);       // cc=0 prefetch

  const int wlocal = l31 * 16 + koff;

  for (int cc = 0; cc < 16; ++cc) {
    __syncthreads();                              // prev compute done
#pragma unroll
    for (int u = 0; u < 4; ++u)
      if (sok[u]) *(f16x8*)(sx + sgp[u] * 24 + sgo[u]) = rx[u];
    __syncthreads();
    if (cc < 15) {                                // overlap next loads w/ compute
      int c0 = (cc + 1) * 16;
#pragma unroll
      for (int u = 0; u < 4; ++u)
        rx[u] = *(const f16x8*)(xh + gbase[u] + c0);
    }
    // 2-deep W fragment pipe
    f16x8 wf = *(const f16x8*)(w + ((cc * 9 + 0) * 16 + et) * 512 + wlocal);
#pragma unroll
    for (int t = 0; t < 9; ++t) {
      f16x8 wcur = wf;
      if (t < 8)
        wf = *(const f16x8*)(w + ((cc * 9 + t + 1) * 16 + et) * 512 + wlocal);
      const int dy = t / 3, dx = t % 3;
      const int dpo = (dy * 50 + dx) * 24 + koff;
#pragma unroll
      for (int nt = 0; nt < 3; ++nt) {
        f16x8 bh = *(const f16x8*)(sx + pb[nt] * 24 + dpo);
        acc[nt] = mfma16(wcur, bh, acc[nt]);
      }
    }
  }

  // epilogue: C/D layout col=lane&31 (=pos), row=(r&3)+8*(r>>2)+4*(lane>>5) (=e)
  const int colh = (lane >> 5) * 4;
#pragma unroll
  for (int nt = 0; nt < 3; ++nt) {
    int n = wvx * 96 + nt * 32 + l31;
    int pos = (y0 + n / 48) * 48 + (n % 48);
    const int jblk = pos >> 5, jl = pos & 31;
    const int jc = pos >> 4, lhv = (pos >> 3) & 1, uv = pos & 7;
#pragma unroll
    for (int g = 0; g < 4; ++g) {
      int eb = e0 + g * 8 + colh;
      f32x4 sb = *(const f32x4*)(bias + eb);
      if constexpr (F == 0) {
        f16x4 hq;
#pragma unroll
        for (int j = 0; j < 4; ++j) hq[j] = (f16)(acc[nt][g * 4 + j] + sb[j]);
        *(f16x4*)(o + ((size_t)b * NN + pos) * NE + eb) = hq;
      } else if constexpr (F == 1) {
        f16x4 hk;
#pragma unroll
        for (int j = 0; j < 4; ++j) hk[j] = (f16)(acc[nt][g * 4 + j] + sb[j]);
        // k_f: [b][pos>>5][eb>>4][((eb>>3)&1)*32 + (pos&31)][eb&7 .. +3]
        *(f16x4*)(o + ((((size_t)b * 72 + jblk) * 32 + (eb >> 4)) * 64 +
                       ((eb >> 3) & 1) * 32 + jl) * 8 + (eb & 7)) = hk;
      } else {
#pragma unroll
        for (int j = 0; j < 4; ++j) {
          int e = eb + j;
          // v_f: [b][e>>5][pos>>4][((pos>>3)&1)*32 + (e&31)][pos&7]
          o[((((size_t)b * 16 + (e >> 5)) * 144 + jc) * 64 + lhv * 32 + (e & 31)) * 8 + uv] =
              (f16)(acc[nt][g * 4 + j] + sb[j]);
        }
      }
    }
  }
}

// ---------------- flash attention v4 (R3-verified, 182 us) ----------------
// Grid 576: b = bid&7 (XCD pin), i-tile = bid>>3 (32 rows). 18 jt of 128 j.
// Phase A: k streamed from global frag blocks (reg pipeline, no barriers),
//          q from persistent LDS. Phase B: lane-local softmax + 2 tiny LDS
//          exchanges (the only 2 barriers). Phase C: v streamed from global,
//          P from sP2. Epilogue: per-lane normalize + residual, direct store.
__global__ __launch_bounds__(256, 3) void attn(
    const f16* __restrict__ qt, const f16* __restrict__ kf,
    const f16* __restrict__ vf, float* __restrict__ out) {
  __shared__ __align__(16) f16 q_lds[32 * QSTR];  // 33792 B, persistent
  __shared__ __align__(16) f16 sP2[4096];         // 8 chunks x 64 lanes x 8 f16
  __shared__ __align__(16) float s_pmax[128];
  __shared__ __align__(16) float s_psum[128];

  const int tid = threadIdx.x;
  const int lane = tid & 63, wvx = tid >> 6;
  const int l31 = lane & 31, lh = lane >> 5;
  const int bid = blockIdx.x;
  const int b = bid & 7;
  const int i0 = (bid >> 3) * 32;

  // ---- load q tile (32 x 512) once, swizzled ----
  {
    const f16* qb = qt + ((size_t)b * NN + i0) * NE;
#pragma unroll
    for (int it = 0; it < 8; ++it) {
      int g = it * 256 + tid;
      int row = g >> 6, gr = g & 63;
      f16x8 v = *(const f16x8*)(qb + row * NE + gr * 8);
      int sgr = (gr & ~7) | ((gr & 7) ^ (row & 7));
      *(f16x8*)(q_lds + row * QSTR + sgr * 8) = v;
    }
  }
  __syncthreads();

  float m_reg = -1e30f, l_reg = 0.f;
  f32x16 O[4];
#pragma unroll
  for (int nt = 0; nt < 4; ++nt)
#pragma unroll
    for (int i = 0; i < 16; ++i) O[nt][i] = 0.f;

  const int x7 = l31 & 7;
  const f16* kfw = kf + (size_t)(b * 72 + wvx) * 16384 + lane * 8;
  const f16* vfw = vf + (size_t)(b * 16 + wvx * 4) * 73728 + lane * 8;
  const f16* qrow = q_lds + l31 * QSTR;

  for (int jt = 0; jt < 18; ++jt) {
    // ---- Phase A: S = k.q^T (swapped) — no barriers ----
    const f16* kfl = kfw + (size_t)jt * 4 * 16384;
    f32x16 S0, S1;
#pragma unroll
    for (int i = 0; i < 16; ++i) { S0[i] = 0.f; S1[i] = 0.f; }
    f16x8 kpipe[6];
#pragma unroll
    for (int t = 0; t < 6; ++t) kpipe[t] = *(const f16x8*)(kfl + t * 512);
    f16x8 qpipe[2];
#pragma unroll
    for (int t = 0; t < 2; ++t) {
      int ga = t * 2 + lh;
      int sg = (ga & ~7) | ((ga & 7) ^ x7);
      qpipe[t] = *(const f16x8*)(qrow + sg * 8);
    }
#pragma unroll
    for (int c = 0; c < 32; ++c) {
      f16x8 ak = kpipe[c % 6];
      if (c + 6 < 32) kpipe[c % 6] = *(const f16x8*)(kfl + (c + 6) * 512);
      f16x8 aq = qpipe[c & 1];
      if (c + 2 < 32) {
        int ga = (c + 2) * 2 + lh;
        int sg = (ga & ~7) | ((ga & 7) ^ x7);
        qpipe[c & 1] = *(const f16x8*)(qrow + sg * 8);
      }
      if (c & 1) S1 = mfma16(ak, aq, S1);
      else       S0 = mfma16(ak, aq, S0);
    }
    f32x16 S;
#pragma unroll
    for (int r = 0; r < 16; ++r) S[r] = S0[r] + S1[r];
    // lane (i=l31, h=lh) holds S[i][j_local = (r&3)+8*(r>>2)+4*lh] for wave's
    // j-block = jt*128 + wvx*32.

    // ---- Phase B: lane-local softmax, 2 barriers ----
    float wmax = S[0];
#pragma unroll
    for (int r = 1; r < 16; ++r) wmax = fmaxf(wmax, S[r]);
    wmax = fmaxf(wmax, __shfl_xor(wmax, 32, 64));
    if (lane < 32) s_pmax[l31 * 4 + wvx] = wmax;
    __syncthreads();                              // barrier 1 (also fences sP2)
    f32x4 pm4 = *(const f32x4*)(s_pmax + l31 * 4);
    float gmax = fmaxf(fmaxf(pm4[0], pm4[1]), fmaxf(pm4[2], pm4[3]));
    float mnew = fmaxf(m_reg, gmax);
    float alpha = __expf(m_reg - mnew);
    m_reg = mnew;

    f16 ph[16];
    float psum = 0.f;
#pragma unroll
    for (int r = 0; r < 16; ++r) {
      f16 p = (f16)__expf(S[r] - mnew);
      ph[r] = p;
      psum += (float)p;
    }
    // pack quads -> B-frags via cross-half exchange, write sP2
    union Q4 { f16x4 h; int i2[2]; };
    Q4 q4[4];
#pragma unroll
    for (int t = 0; t < 4; ++t)
#pragma unroll
      for (int u = 0; u < 4; ++u) q4[t].h[u] = ph[t * 4 + u];
#pragma unroll
    for (int ks = 0; ks < 2; ++ks) {
      Q4 t1, t2;
      t1.i2[0] = __shfl_xor(q4[2 * ks + 1].i2[0], 32, 64);
      t1.i2[1] = __shfl_xor(q4[2 * ks + 1].i2[1], 32, 64);
      t2.i2[0] = __shfl_xor(q4[2 * ks].i2[0], 32, 64);
      t2.i2[1] = __shfl_xor(q4[2 * ks].i2[1], 32, 64);
      f16x4 first  = lh ? t1.h : q4[2 * ks].h;
      f16x4 second = lh ? q4[2 * ks + 1].h : t2.h;
      f16x8 frag;
#pragma unroll
      for (int u = 0; u < 4; ++u) { frag[u] = first[u]; frag[4 + u] = second[u]; }
      *(f16x8*)(sP2 + ((wvx * 2 + ks) * 64 + lane) * 8) = frag;
    }
    psum += __shfl_xor(psum, 32, 64);
    if (lane < 32) s_psum[l31 * 4 + wvx] = psum;
    // rescale O while the exchange settles
#pragma unroll
    for (int nt = 0; nt < 4; ++nt)
#pragma unroll
      for (int r = 0; r < 16; ++r) O[nt][r] *= alpha;
    __syncthreads();                              // barrier 2 (P + sums visible)
    f32x4 ps4 = *(const f32x4*)(s_psum + l31 * 4);
    l_reg = l_reg * alpha + (ps4[0] + ps4[1] + ps4[2] + ps4[3]);

    // ---- Phase C: O += V.P (A=v frag stream, B=P from sP2) — no barriers ----
    const f16* vfl = vfw + (size_t)jt * 8 * 512;
    f16x8 vpipe[6];
#pragma unroll
    for (int t = 0; t < 6; ++t) {
      int nt = t & 3, cg = t >> 2;
      vpipe[t] = *(const f16x8*)(vfl + (size_t)nt * 73728 + cg * 512);
    }
    f16x8 apc = *(const f16x8*)(sP2 + (0 * 64 + lane) * 8);
    f16x8 apn = *(const f16x8*)(sP2 + (1 * 64 + lane) * 8);
#pragma unroll
    for (int c = 0; c < 32; ++c) {
      int nt = c & 3, cg = c >> 2;
      f16x8 av = vpipe[c % 6];
      if (c + 6 < 32) {
        int nt2 = (c + 6) & 3, cg2 = (c + 6) >> 2;
        vpipe[c % 6] = *(const f16x8*)(vfl + (size_t)nt2 * 73728 + cg2 * 512);
      }
      O[nt] = mfma16(av, apc, O[nt]);
      if (nt == 3) {
        apc = apn;
        if (cg + 2 < 8) apn = *(const f16x8*)(sP2 + ((cg + 2) * 64 + lane) * 8);
      }
    }
  }

  // ---- epilogue: per-lane normalize + v residual, direct coalesced stores ----
  float inv = 1.0f / l_reg;
  const int ii = i0 + l31;
  const int jcR = ii >> 4, lhR = (ii >> 3) & 1, uR = ii & 7;
#pragma unroll
  for (int nt = 0; nt < 4; ++nt) {
    const f16* vres = vf + ((((size_t)(b * 16 + wvx * 4 + nt)) * 144 + jcR) * 64 + lhR * 32) * 8 + uR;
    const int ebase = wvx * 128 + nt * 32;
#pragma unroll
    for (int r = 0; r < 16; ++r) {
      int el = (r & 3) + 8 * (r >> 2) + 4 * lh;
      float rv = (float)vres[el * 8];
      out[((size_t)b * NE + ebase + el) * NN + ii] = O[nt][r] * inv + rv;
    }
  }
}

// ---------------- launch ----------------
extern "C" void kernel_launch(void* const* d_in, const int* in_sizes, int n_in,
                              void* d_out, int out_size, void* d_ws, size_t ws_size,
                              hipStream_t stream) {
  const float* feat = (const float*)d_in[0];
  const float* Wq = (const float*)d_in[1];
  const float* bq = (const float*)d_in[2];
  const float* Wk = (const float*)d_in[3];
  const float* bk = (const float*)d_in[4];
  const float* Wv = (const float*)d_in[5];
  const float* bv = (const float*)d_in[6];
  float* out = (float*)d_out;

  char* ws = (char*)d_ws;
  size_t off = 0;
  auto alloc = [&](size_t bytes) {
    void* p = ws + off;
    off += (bytes + 255) & ~(size_t)255;
    return p;
  };
  const size_t FP = (size_t)NB * HP * HP * NC;     // 5,120,000
  const size_t WP = (size_t)9 * NE * NC;           // 1,179,648
  const size_t QP = (size_t)NB * NN * NE;          // 9,437,184
  f16* fp  = (f16*)alloc(FP * 2);
  f16* wq  = (f16*)alloc(WP * 2);
  f16* wk  = (f16*)alloc(WP * 2);
  f16* wv  = (f16*)alloc(WP * 2);
  f16* q_t = (f16*)alloc(QP * 2);
  f16* k_f = (f16*)alloc(QP * 2);
  f16* v_f = (f16*)alloc(QP * 2);

  pack_feat<<<dim3(FP / 256), dim3(256), 0, stream>>>(feat, fp);
  pack_w<<<dim3(WP / 256), dim3(256), 0, stream>>>(Wq, Wk, Wv, wq, wk, wv);

  conv3_one<0><<<dim3(16, 48), dim3(256), 0, stream>>>(fp, wq, bq, q_t);
  conv3_one<1><<<dim3(16, 48), dim3(256), 0, stream>>>(fp, wk, bk, k_f);
  conv3_one<2><<<dim3(16, 48), dim3(256), 0, stream>>>(fp, wv, bv, v_f);

  attn<<<dim3(576), dim3(256), 0, stream>>>(q_t, k_f, v_f, out);
}

// Round 8
// 443.820 us; speedup vs baseline: 2.0440x; 1.0275x over previous
//
#include <hip/hip_runtime.h>

// ConvSA: B=8, C=256, H=W=48 (N=2304), E=512.
// out[b,e,i] = sum_j softmax_j(q[:,i].k[:,j]) * v[e,j] + v[e,i]
// R8 = attn v4 (R3/R7-verified, 182 us) with frag-block q_lds (R4/R6-verified
// conflict-free layout) + conv with LDS DOUBLE-BUFFERED staging:
//  - conv: 1 barrier/cc (was 2); ds_writes overlap compute (other buffer);
//    3 convs merged into one launch (grid 16x48x3, runtime F) -> no
//    inter-kernel drains, q/k/v blocks of one tile share an XCD's X slab.
//    R3 vs R7 equality showed conv is barrier-stall-bound, not LDS/occupancy.
//  - attn: swapped QK^T lane-local softmax, k/v global frag streams
//    (depth-6 pipes), q in 32x1KB linear frag blocks (ds_read_b128,
//    immediate offsets, no swizzle VALU), 2 barriers/jt.

typedef _Float16 f16;
typedef _Float16 f16x4 __attribute__((ext_vector_type(4)));
typedef _Float16 f16x8 __attribute__((ext_vector_type(8)));
typedef float    f32x4  __attribute__((ext_vector_type(4)));
typedef float    f32x16 __attribute__((ext_vector_type(16)));

__device__ __forceinline__ f32x16 mfma16(f16x8 a, f16x8 b, f32x16 c) {
  return __builtin_amdgcn_mfma_f32_32x32x16_f16(a, b, c, 0, 0, 0);
}

#define NB   8
#define NC   256
#define NH   48
#define NN   2304     // 48*48
#define NE   512
#define HP   50       // padded H/W

// ---------------- pack kernels ----------------

// feat NCHW fp32 -> zero-padded NHWC [b][50][50][256] fp16
__global__ void pack_feat(const float* __restrict__ x, f16* __restrict__ p) {
  int idx = blockIdx.x * 256 + threadIdx.x;       // 8*50*50*256
  int c  = idx & 255;
  int q  = idx >> 8;
  int xp = q % 50; int t = q / 50; int yp = t % 50; int b = t / 50;
  float v = 0.f;
  if (yp >= 1 && yp <= 48 && xp >= 1 && xp <= 48)
    v = x[((b * NC + c) * NH + (yp - 1)) * NH + (xp - 1)];
  p[idx] = (f16)v;
}

// W OIHW [512][256][3][3] fp32 -> A-frag blocks:
// [cc 16][t 9][et 16] x (el 32 x cl 16) contiguous 512-f16 (1 KB) blocks.
__global__ void pack_w(const float* __restrict__ wq, const float* __restrict__ wk,
                       const float* __restrict__ wv,
                       f16* __restrict__ oq, f16* __restrict__ ok,
                       f16* __restrict__ ov) {
  int idx = blockIdx.x * 256 + threadIdx.x;       // 9*512*256
  int c = idx & 255;
  int r = idx >> 8;
  int e = r & 511; int t = r >> 9;
  int src = (e * NC + c) * 9 + t;
  int cc = c >> 4, cl = c & 15, et = e >> 5, el = e & 31;
  int dst = ((cc * 9 + t) * 16 + et) * 512 + el * 16 + cl;
  oq[dst] = (f16)wq[src];
  ok[dst] = (f16)wk[src];
  ov[dst] = (f16)wv[src];
}

// ---------------- implicit-GEMM conv3x3, dbuf staging, merged q/k/v ----------------
// Block 256 thr; out tile 32 e x 384 pos; grid (16 e-tiles, 48, 3 outputs).
// F = blockIdx.z: 0 -> q row-major; 1 -> k_f frag blocks; 2 -> v_f frag blocks.
// LDS: 2 x (500 pos x 24 f16) = 48 KB -> 3 blocks/CU. ONE barrier per cc.
__global__ __launch_bounds__(256, 3) void conv3_all(
    const f16* __restrict__ xh,
    const f16* __restrict__ wq, const f16* __restrict__ wk,
    const f16* __restrict__ wv,
    const float* __restrict__ bq, const float* __restrict__ bk,
    const float* __restrict__ bv,
    f16* __restrict__ oq, f16* __restrict__ okf, f16* __restrict__ ovf) {
  __shared__ __align__(16) f16 sx[2][12000];      // 2 x 24 KB

  const int tid = threadIdx.x;
  const int lane = tid & 63, wvx = tid >> 6;
  const int l31 = lane & 31;
  const int koff = (lane >> 5) * 8;
  const int et = blockIdx.x;
  const int e0 = et * 32;
  const int by = blockIdx.y;
  const int b = by / 6, strip = by % 6;
  const int y0 = strip * 8;
  const int F = blockIdx.z;
  const f16* w = (F == 0) ? wq : (F == 1) ? wk : wv;
  const float* bias = (F == 0) ? bq : (F == 1) ? bk : bv;

  int pb[3];
#pragma unroll
  for (int nt = 0; nt < 3; ++nt) {
    int n = wvx * 96 + nt * 32 + l31;
    pb[nt] = (n / 48) * 50 + (n % 48);
  }

  // staging coords: 4 chunks/thread
  int sgp[4], sgo[4]; bool sok[4]; int gbase[4];
#pragma unroll
  for (int u = 0; u < 4; ++u) {
    int g = u * 256 + tid;
    sok[u] = (g < 1000);
    int gg = sok[u] ? g : 999;
    sgp[u] = gg >> 1; sgo[u] = (gg & 1) * 8;
    int row = sgp[u] / 50, xx = sgp[u] % 50;
    gbase[u] = ((b * HP + y0 + row) * HP + xx) * NC + sgo[u];
  }

  f32x16 acc[3];
#pragma unroll
  for (int nt = 0; nt < 3; ++nt)
#pragma unroll
    for (int i = 0; i < 16; ++i) acc[nt][i] = 0.f;

  const int wlocal = l31 * 16 + koff;

  // prologue: load + write chunk 0 into buffer 0
  {
    f16x8 rx0[4];
#pragma unroll
    for (int u = 0; u < 4; ++u)
      rx0[u] = *(const f16x8*)(xh + gbase[u]);
#pragma unroll
    for (int u = 0; u < 4; ++u)
      if (sok[u]) *(f16x8*)(sx[0] + sgp[u] * 24 + sgo[u]) = rx0[u];
  }
  __syncthreads();

  for (int cc = 0; cc < 16; ++cc) {
    f16x8 rx[4];
    if (cc < 15) {                                // issue next-chunk loads early
      int c0 = (cc + 1) * 16;
#pragma unroll
      for (int u = 0; u < 4; ++u)
        rx[u] = *(const f16x8*)(xh + gbase[u] + c0);
    }
    const f16* sxc = sx[cc & 1];
    // 2-deep W fragment pipe
    f16x8 wf = *(const f16x8*)(w + ((cc * 9 + 0) * 16 + et) * 512 + wlocal);
#pragma unroll
    for (int t = 0; t < 9; ++t) {
      f16x8 wcur = wf;
      if (t < 8)
        wf = *(const f16x8*)(w + ((cc * 9 + t + 1) * 16 + et) * 512 + wlocal);
      const int dy = t / 3, dx = t % 3;
      const int dpo = (dy * 50 + dx) * 24 + koff;
#pragma unroll
      for (int nt = 0; nt < 3; ++nt) {
        f16x8 bh = *(const f16x8*)(sxc + pb[nt] * 24 + dpo);
        acc[nt] = mfma16(wcur, bh, acc[nt]);
      }
    }
    if (cc < 15) {                                // write OTHER buffer (overlaps)
#pragma unroll
      for (int u = 0; u < 4; ++u)
        if (sok[u]) *(f16x8*)(sx[(cc + 1) & 1] + sgp[u] * 24 + sgo[u]) = rx[u];
    }
    __syncthreads();                              // ONE barrier per cc
  }

  // epilogue: C/D layout col=lane&31 (=pos), row=(r&3)+8*(r>>2)+4*(lane>>5) (=e)
  const int colh = (lane >> 5) * 4;
#pragma unroll
  for (int nt = 0; nt < 3; ++nt) {
    int n = wvx * 96 + nt * 32 + l31;
    int pos = (y0 + n / 48) * 48 + (n % 48);
    const int jblk = pos >> 5, jl = pos & 31;
    const int jc = pos >> 4, lhv = (pos >> 3) & 1, uv = pos & 7;
#pragma unroll
    for (int g = 0; g < 4; ++g) {
      int eb = e0 + g * 8 + colh;
      f32x4 sb = *(const f32x4*)(bias + eb);
      if (F == 0) {
        f16x4 hq;
#pragma unroll
        for (int j = 0; j < 4; ++j) hq[j] = (f16)(acc[nt][g * 4 + j] + sb[j]);
        *(f16x4*)(oq + ((size_t)b * NN + pos) * NE + eb) = hq;
      } else if (F == 1) {
        f16x4 hk;
#pragma unroll
        for (int j = 0; j < 4; ++j) hk[j] = (f16)(acc[nt][g * 4 + j] + sb[j]);
        // k_f: [b][pos>>5][eb>>4][((eb>>3)&1)*32 + (pos&31)][eb&7 .. +3]
        *(f16x4*)(okf + ((((size_t)b * 72 + jblk) * 32 + (eb >> 4)) * 64 +
                         ((eb >> 3) & 1) * 32 + jl) * 8 + (eb & 7)) = hk;
      } else {
#pragma unroll
        for (int j = 0; j < 4; ++j) {
          int e = eb + j;
          // v_f: [b][e>>5][pos>>4][((pos>>3)&1)*32 + (e&31)][pos&7]
          ovf[((((size_t)b * 16 + (e >> 5)) * 144 + jc) * 64 + lhv * 32 + (e & 31)) * 8 + uv] =
              (f16)(acc[nt][g * 4 + j] + sb[j]);
        }
      }
    }
  }
}

// ---------------- flash attention v4 (frag-block q_lds) ----------------
// Grid 576: b = bid&7 (XCD pin), i-tile = bid>>3 (32 rows). 18 jt of 128 j.
// Phase A: k streamed from global frag blocks (depth-6 reg pipe), q from
//          persistent LDS frag blocks (conflict-free, immediate offsets).
// Phase B: lane-local softmax + 2 tiny LDS exchanges (the only 2 barriers).
// Phase C: v streamed from global, P from sP2.
// Epilogue: per-lane normalize + residual, direct coalesced stores.
__global__ __launch_bounds__(256, 3) void attn(
    const f16* __restrict__ qt, const f16* __restrict__ kf,
    const f16* __restrict__ vf, float* __restrict__ out) {
  __shared__ __align__(16) f16 q_lds[16384];      // 32 frag blocks x 512 f16 = 32 KB
  __shared__ __align__(16) f16 sP2[4096];         // 8 chunks x 64 lanes x 8 f16
  __shared__ __align__(16) float s_pmax[128];
  __shared__ __align__(16) float s_psum[128];

  const int tid = threadIdx.x;
  const int lane = tid & 63, wvx = tid >> 6;
  const int l31 = lane & 31, lh = lane >> 5;
  const int bid = blockIdx.x;
  const int b = bid & 7;
  const int i0 = (bid >> 3) * 32;

  // ---- stage q tile (32 x 512) once, into frag-block layout ----
  {
    const f16* qb = qt + ((size_t)b * NN + i0) * NE;
#pragma unroll
    for (int it = 0; it < 8; ++it) {
      int g = it * 256 + tid;
      int row = g >> 6, gr = g & 63;
      f16x8 v = *(const f16x8*)(qb + row * NE + gr * 8);
      // frag block ec=gr>>1: lane' = (gr&1)*32 + row, inner = e&7
      *(f16x8*)(q_lds + (gr >> 1) * 512 + (gr & 1) * 256 + row * 8) = v;
    }
  }
  __syncthreads();

  float m_reg = -1e30f, l_reg = 0.f;
  f32x16 O[4];
#pragma unroll
  for (int nt = 0; nt < 4; ++nt)
#pragma unroll
    for (int i = 0; i < 16; ++i) O[nt][i] = 0.f;

  const f16* kfw = kf + (size_t)(b * 72 + wvx) * 16384 + lane * 8;
  const f16* vfw = vf + (size_t)(b * 16 + wvx * 4) * 73728 + lane * 8;
  const f16* qlw = q_lds + lane * 8;

  for (int jt = 0; jt < 18; ++jt) {
    // ---- Phase A: S = k.q^T (swapped) — no barriers ----
    const f16* kfl = kfw + (size_t)jt * 4 * 16384;
    f32x16 S0, S1;
#pragma unroll
    for (int i = 0; i < 16; ++i) { S0[i] = 0.f; S1[i] = 0.f; }
    f16x8 kpipe[6];
#pragma unroll
    for (int t = 0; t < 6; ++t) kpipe[t] = *(const f16x8*)(kfl + t * 512);
#pragma unroll
    for (int c = 0; c < 32; ++c) {
      f16x8 ak = kpipe[c % 6];
      if (c + 6 < 32) kpipe[c % 6] = *(const f16x8*)(kfl + (c + 6) * 512);
      f16x8 aq = *(const f16x8*)(qlw + c * 512);
      if (c & 1) S1 = mfma16(ak, aq, S1);
      else       S0 = mfma16(ak, aq, S0);
    }
    f32x16 S;
#pragma unroll
    for (int r = 0; r < 16; ++r) S[r] = S0[r] + S1[r];
    // lane (i=l31, h=lh) holds S[i][j_local = (r&3)+8*(r>>2)+4*lh] for wave's
    // j-block = jt*128 + wvx*32.

    // ---- Phase B: lane-local softmax, 2 barriers ----
    float wmax = S[0];
#pragma unroll
    for (int r = 1; r < 16; ++r) wmax = fmaxf(wmax, S[r]);
    wmax = fmaxf(wmax, __shfl_xor(wmax, 32, 64));
    if (lane < 32) s_pmax[l31 * 4 + wvx] = wmax;
    __syncthreads();                              // barrier 1 (also fences sP2)
    f32x4 pm4 = *(const f32x4*)(s_pmax + l31 * 4);
    float gmax = fmaxf(fmaxf(pm4[0], pm4[1]), fmaxf(pm4[2], pm4[3]));
    float mnew = fmaxf(m_reg, gmax);
    float alpha = __expf(m_reg - mnew);
    m_reg = mnew;

    f16 ph[16];
    float psum = 0.f;
#pragma unroll
    for (int r = 0; r < 16; ++r) {
      f16 p = (f16)__expf(S[r] - mnew);
      ph[r] = p;
      psum += (float)p;
    }
    // pack quads -> B-frags via cross-half exchange, write sP2
    union Q4 { f16x4 h; int i2[2]; };
    Q4 q4[4];
#pragma unroll
    for (int t = 0; t < 4; ++t)
#pragma unroll
      for (int u = 0; u < 4; ++u) q4[t].h[u] = ph[t * 4 + u];
#pragma unroll
    for (int ks = 0; ks < 2; ++ks) {
      Q4 t1, t2;
      t1.i2[0] = __shfl_xor(q4[2 * ks + 1].i2[0], 32, 64);
      t1.i2[1] = __shfl_xor(q4[2 * ks + 1].i2[1], 32, 64);
      t2.i2[0] = __shfl_xor(q4[2 * ks].i2[0], 32, 64);
      t2.i2[1] = __shfl_xor(q4[2 * ks].i2[1], 32, 64);
      f16x4 first  = lh ? t1.h : q4[2 * ks].h;
      f16x4 second = lh ? q4[2 * ks + 1].h : t2.h;
      f16x8 frag;
#pragma unroll
      for (int u = 0; u < 4; ++u) { frag[u] = first[u]; frag[4 + u] = second[u]; }
      *(f16x8*)(sP2 + ((wvx * 2 + ks) * 64 + lane) * 8) = frag;
    }
    psum += __shfl_xor(psum, 32, 64);
    if (lane < 32) s_psum[l31 * 4 + wvx] = psum;
    // rescale O while the exchange settles
#pragma unroll
    for (int nt = 0; nt < 4; ++nt)
#pragma unroll
      for (int r = 0; r < 16; ++r) O[nt][r] *= alpha;
    __syncthreads();                              // barrier 2 (P + sums visible)
    f32x4 ps4 = *(const f32x4*)(s_psum + l31 * 4);
    l_reg = l_reg * alpha + (ps4[0] + ps4[1] + ps4[2] + ps4[3]);

    // ---- Phase C: O += V.P (A=v frag stream, B=P from sP2) — no barriers ----
    const f16* vfl = vfw + (size_t)jt * 8 * 512;
    f16x8 vpipe[6];
#pragma unroll
    for (int t = 0; t < 6; ++t) {
      int nt = t & 3, cg = t >> 2;
      vpipe[t] = *(const f16x8*)(vfl + (size_t)nt * 73728 + cg * 512);
    }
    f16x8 apc = *(const f16x8*)(sP2 + (0 * 64 + lane) * 8);
    f16x8 apn = *(const f16x8*)(sP2 + (1 * 64 + lane) * 8);
#pragma unroll
    for (int c = 0; c < 32; ++c) {
      int nt = c & 3, cg = c >> 2;
      f16x8 av = vpipe[c % 6];
      if (c + 6 < 32) {
        int nt2 = (c + 6) & 3, cg2 = (c + 6) >> 2;
        vpipe[c % 6] = *(const f16x8*)(vfl + (size_t)nt2 * 73728 + cg2 * 512);
      }
      O[nt] = mfma16(av, apc, O[nt]);
      if (nt == 3) {
        apc = apn;
        if (cg + 2 < 8) apn = *(const f16x8*)(sP2 + ((cg + 2) * 64 + lane) * 8);
      }
    }
  }

  // ---- epilogue: per-lane normalize + v residual, direct coalesced stores ----
  float inv = 1.0f / l_reg;
  const int ii = i0 + l31;
  const int jcR = ii >> 4, lhR = (ii >> 3) & 1, uR = ii & 7;
#pragma unroll
  for (int nt = 0; nt < 4; ++nt) {
    const f16* vres = vf + ((((size_t)(b * 16 + wvx * 4 + nt)) * 144 + jcR) * 64 + lhR * 32) * 8 + uR;
    const int ebase = wvx * 128 + nt * 32;
#pragma unroll
    for (int r = 0; r < 16; ++r) {
      int el = (r & 3) + 8 * (r >> 2) + 4 * lh;
      float rv = (float)vres[el * 8];
      out[((size_t)b * NE + ebase + el) * NN + ii] = O[nt][r] * inv + rv;
    }
  }
}

// ---------------- launch ----------------
extern "C" void kernel_launch(void* const* d_in, const int* in_sizes, int n_in,
                              void* d_out, int out_size, void* d_ws, size_t ws_size,
                              hipStream_t stream) {
  const float* feat = (const float*)d_in[0];
  const float* Wq = (const float*)d_in[1];
  const float* bq = (const float*)d_in[2];
  const float* Wk = (const float*)d_in[3];
  const float* bk = (const float*)d_in[4];
  const float* Wv = (const float*)d_in[5];
  const float* bv = (const float*)d_in[6];
  float* out = (float*)d_out;

  char* ws = (char*)d_ws;
  size_t off = 0;
  auto alloc = [&](size_t bytes) {
    void* p = ws + off;
    off += (bytes + 255) & ~(size_t)255;
    return p;
  };
  const size_t FP = (size_t)NB * HP * HP * NC;     // 5,120,000
  const size_t WP = (size_t)9 * NE * NC;           // 1,179,648
  const size_t QP = (size_t)NB * NN * NE;          // 9,437,184
  f16* fp  = (f16*)alloc(FP * 2);
  f16* wq  = (f16*)alloc(WP * 2);
  f16* wk  = (f16*)alloc(WP * 2);
  f16* wv  = (f16*)alloc(WP * 2);
  f16* q_t = (f16*)alloc(QP * 2);
  f16* k_f = (f16*)alloc(QP * 2);
  f16* v_f = (f16*)alloc(QP * 2);

  pack_feat<<<dim3(FP / 256), dim3(256), 0, stream>>>(feat, fp);
  pack_w<<<dim3(WP / 256), dim3(256), 0, stream>>>(Wq, Wk, Wv, wq, wk, wv);

  conv3_all<<<dim3(16, 48, 3), dim3(256), 0, stream>>>(
      fp, wq, wk, wv, bq, bk, bv, q_t, k_f, v_f);

  attn<<<dim3(576), dim3(256), 0, stream>>>(q_t, k_f, v_f, out);
}

// Round 9
// 434.899 us; speedup vs baseline: 2.0859x; 1.0205x over previous
//
#include <hip/hip_runtime.h>

// ConvSA: B=8, C=256, H=W=48 (N=2304), E=512.
// out[b,e,i] = sum_j softmax_j(q[:,i].k[:,j]) * v[e,j] + v[e,i]
// R9: attack load latency everywhere (R8 showed conflicts/barriers were not it):
//  - attn v6: k/v pipes 6->12 deep; k(jt+1)[0..11] issued at top of Phase C
//    (no barrier between C and next A); v(jt)[0..11] issued right after
//    Phase A (drains during softmax/barriers). ~90 free regs at 2 waves/SIMD
//    absorb the pipes (VGPR was 72; budget 256).
//  - conv: preload ALL 9 W frags per cc (36 regs) -> one L2 latency per cc
//    instead of nine (R3 no-pipe == R7 2-deep proved distance-1 is useless).
//  - pack_feat: LDS-transposed coalesced pack (was stride-9216B reads,
//    16x over-fetch ~= 300 MB); grid (8 b, 50 yp), conflict-free padded tile.

typedef _Float16 f16;
typedef _Float16 f16x4 __attribute__((ext_vector_type(4)));
typedef _Float16 f16x8 __attribute__((ext_vector_type(8)));
typedef float    f32x4  __attribute__((ext_vector_type(4)));
typedef float    f32x16 __attribute__((ext_vector_type(16)));

__device__ __forceinline__ f32x16 mfma16(f16x8 a, f16x8 b, f32x16 c) {
  return __builtin_amdgcn_mfma_f32_32x32x16_f16(a, b, c, 0, 0, 0);
}

__device__ __forceinline__ f16x8 f16x8_zero() {
  f16x8 z;
#pragma unroll
  for (int j = 0; j < 8; ++j) z[j] = (f16)0.f;
  return z;
}

#define NB   8
#define NC   256
#define NH   48
#define NN   2304     // 48*48
#define NE   512
#define HP   50       // padded H/W

// ---------------- pack kernels ----------------

// feat NCHW fp32 -> zero-padded NHWC [b][50][50][256] fp16.
// Coalesced: grid (8 b, 50 yp); interior rows via LDS transpose tile [x][c]
// (pad 258 -> conflict-free); border rows/cols zeroed here too.
__global__ void pack_feat(const float* __restrict__ x, f16* __restrict__ p) {
  __shared__ f16 tx[48 * 258];                    // 24768 f16 = 49.5 KB
  const int b = blockIdx.x, yp = blockIdx.y;
  const int tid = threadIdx.x;
  f16* prow = p + ((size_t)(b * HP + yp) * HP) * NC;

  if (yp == 0 || yp == HP - 1) {                  // zero rows
    for (int i = tid; i < 1600; i += 256)
      *(f16x8*)(prow + i * 8) = f16x8_zero();
    return;
  }
  const int y = yp - 1;
  // read: coalesced along x. i = it*256+tid: xsl = i&63 (lane), c = i>>6.
#pragma unroll 4
  for (int it = 0; it < 64; ++it) {
    int i = it * 256 + tid;
    int xsl = i & 63, c = i >> 6;
    if (xsl < 48) {
      float v = x[((b * NC + c) * NH + y) * NH + xsl];
      tx[xsl * 258 + c] = (f16)v;
    }
  }
  __syncthreads();
  // write interior: c0 = (tid&31)*8 fastest -> coalesced 512B runs.
#pragma unroll
  for (int it = 0; it < 6; ++it) {
    int xq = (tid >> 5) + it * 8;
    int c0 = (tid & 31) * 8;
    f16x8 v = *(const f16x8*)(tx + xq * 258 + c0);
    *(f16x8*)(prow + (xq + 1) * NC + c0) = v;
  }
  // border cols xp = 0 and 49
  if (tid < 64) {
    int xp = (tid >> 5) * (HP - 1);
    int c0 = (tid & 31) * 8;
    *(f16x8*)(prow + xp * NC + c0) = f16x8_zero();
  }
}

// W OIHW [512][256][3][3] fp32 -> A-frag blocks:
// [cc 16][t 9][et 16] x (el 32 x cl 16) contiguous 512-f16 (1 KB) blocks.
__global__ void pack_w(const float* __restrict__ wq, const float* __restrict__ wk,
                       const float* __restrict__ wv,
                       f16* __restrict__ oq, f16* __restrict__ ok,
                       f16* __restrict__ ov) {
  int idx = blockIdx.x * 256 + threadIdx.x;       // 9*512*256
  int c = idx & 255;
  int r = idx >> 8;
  int e = r & 511; int t = r >> 9;
  int src = (e * NC + c) * 9 + t;
  int cc = c >> 4, cl = c & 15, et = e >> 5, el = e & 31;
  int dst = ((cc * 9 + t) * 16 + et) * 512 + el * 16 + cl;
  oq[dst] = (f16)wq[src];
  ok[dst] = (f16)wk[src];
  ov[dst] = (f16)wv[src];
}

// ---------------- implicit-GEMM conv3x3, dbuf staging, merged q/k/v ----------------
// Block 256 thr; out tile 32 e x 384 pos; grid (16 e-tiles, 48, 3 outputs).
// F = blockIdx.z: 0 -> q row-major; 1 -> k_f frag blocks; 2 -> v_f frag blocks.
// LDS: 2 x 24 KB X dbuf -> 3 blocks/CU. ONE barrier per cc. W: full-9 preload.
__global__ __launch_bounds__(256, 3) void conv3_all(
    const f16* __restrict__ xh,
    const f16* __restrict__ wq, const f16* __restrict__ wk,
    const f16* __restrict__ wv,
    const float* __restrict__ bq, const float* __restrict__ bk,
    const float* __restrict__ bv,
    f16* __restrict__ oq, f16* __restrict__ okf, f16* __restrict__ ovf) {
  __shared__ __align__(16) f16 sx[2][12000];      // 2 x 24 KB

  const int tid = threadIdx.x;
  const int lane = tid & 63, wvx = tid >> 6;
  const int l31 = lane & 31;
  const int koff = (lane >> 5) * 8;
  const int et = blockIdx.x;
  const int e0 = et * 32;
  const int by = blockIdx.y;
  const int b = by / 6, strip = by % 6;
  const int y0 = strip * 8;
  const int F = blockIdx.z;
  const f16* w = (F == 0) ? wq : (F == 1) ? wk : wv;
  const float* bias = (F == 0) ? bq : (F == 1) ? bk : bv;

  int pb[3];
#pragma unroll
  for (int nt = 0; nt < 3; ++nt) {
    int n = wvx * 96 + nt * 32 + l31;
    pb[nt] = (n / 48) * 50 + (n % 48);
  }

  // staging coords: 4 chunks/thread
  int sgp[4], sgo[4]; bool sok[4]; int gbase[4];
#pragma unroll
  for (int u = 0; u < 4; ++u) {
    int g = u * 256 + tid;
    sok[u] = (g < 1000);
    int gg = sok[u] ? g : 999;
    sgp[u] = gg >> 1; sgo[u] = (gg & 1) * 8;
    int row = sgp[u] / 50, xx = sgp[u] % 50;
    gbase[u] = ((b * HP + y0 + row) * HP + xx) * NC + sgo[u];
  }

  f32x16 acc[3];
#pragma unroll
  for (int nt = 0; nt < 3; ++nt)
#pragma unroll
    for (int i = 0; i < 16; ++i) acc[nt][i] = 0.f;

  const int wlocal = l31 * 16 + koff;

  // prologue: load + write chunk 0 into buffer 0
  {
    f16x8 rx0[4];
#pragma unroll
    for (int u = 0; u < 4; ++u)
      rx0[u] = *(const f16x8*)(xh + gbase[u]);
#pragma unroll
    for (int u = 0; u < 4; ++u)
      if (sok[u]) *(f16x8*)(sx[0] + sgp[u] * 24 + sgo[u]) = rx0[u];
  }
  __syncthreads();

  for (int cc = 0; cc < 16; ++cc) {
    // preload ALL 9 W fragments for this cc (one latency, then streamed)
    f16x8 wreg[9];
#pragma unroll
    for (int t = 0; t < 9; ++t)
      wreg[t] = *(const f16x8*)(w + ((cc * 9 + t) * 16 + et) * 512 + wlocal);
    f16x8 rx[4];
    if (cc < 15) {                                // issue next-chunk X loads
      int c0 = (cc + 1) * 16;
#pragma unroll
      for (int u = 0; u < 4; ++u)
        rx[u] = *(const f16x8*)(xh + gbase[u] + c0);
    }
    const f16* sxc = sx[cc & 1];
#pragma unroll
    for (int t = 0; t < 9; ++t) {
      const int dy = t / 3, dx = t % 3;
      const int dpo = (dy * 50 + dx) * 24 + koff;
#pragma unroll
      for (int nt = 0; nt < 3; ++nt) {
        f16x8 bh = *(const f16x8*)(sxc + pb[nt] * 24 + dpo);
        acc[nt] = mfma16(wreg[t], bh, acc[nt]);
      }
    }
    if (cc < 15) {                                // write OTHER buffer (overlaps)
#pragma unroll
      for (int u = 0; u < 4; ++u)
        if (sok[u]) *(f16x8*)(sx[(cc + 1) & 1] + sgp[u] * 24 + sgo[u]) = rx[u];
    }
    __syncthreads();                              // ONE barrier per cc
  }

  // epilogue: C/D layout col=lane&31 (=pos), row=(r&3)+8*(r>>2)+4*(lane>>5) (=e)
  const int colh = (lane >> 5) * 4;
#pragma unroll
  for (int nt = 0; nt < 3; ++nt) {
    int n = wvx * 96 + nt * 32 + l31;
    int pos = (y0 + n / 48) * 48 + (n % 48);
    const int jblk = pos >> 5, jl = pos & 31;
    const int jc = pos >> 4, lhv = (pos >> 3) & 1, uv = pos & 7;
#pragma unroll
    for (int g = 0; g < 4; ++g) {
      int eb = e0 + g * 8 + colh;
      f32x4 sb = *(const f32x4*)(bias + eb);
      if (F == 0) {
        f16x4 hq;
#pragma unroll
        for (int j = 0; j < 4; ++j) hq[j] = (f16)(acc[nt][g * 4 + j] + sb[j]);
        *(f16x4*)(oq + ((size_t)b * NN + pos) * NE + eb) = hq;
      } else if (F == 1) {
        f16x4 hk;
#pragma unroll
        for (int j = 0; j < 4; ++j) hk[j] = (f16)(acc[nt][g * 4 + j] + sb[j]);
        // k_f: [b][pos>>5][eb>>4][((eb>>3)&1)*32 + (pos&31)][eb&7 .. +3]
        *(f16x4*)(okf + ((((size_t)b * 72 + jblk) * 32 + (eb >> 4)) * 64 +
                         ((eb >> 3) & 1) * 32 + jl) * 8 + (eb & 7)) = hk;
      } else {
#pragma unroll
        for (int j = 0; j < 4; ++j) {
          int e = eb + j;
          // v_f: [b][e>>5][pos>>4][((pos>>3)&1)*32 + (e&31)][pos&7]
          ovf[((((size_t)b * 16 + (e >> 5)) * 144 + jc) * 64 + lhv * 32 + (e & 31)) * 8 + uv] =
              (f16)(acc[nt][g * 4 + j] + sb[j]);
        }
      }
    }
  }
}

// ---------------- flash attention v6 (deep pipes + cross-phase prefetch) --------
// Grid 576: b = bid&7 (XCD pin), i-tile = bid>>3 (32 rows). 18 jt of 128 j.
// Phase A: k stream depth-12 (first 12 pre-issued during previous Phase C);
//          q from persistent LDS frag blocks. After A: issue v[0..11] (drain
//          under softmax/barriers). Phase B: lane-local softmax, 2 barriers.
// Phase C: top issues k(jt+1)[0..11]; v stream depth-12.
__global__ __launch_bounds__(256, 2) void attn(
    const f16* __restrict__ qt, const f16* __restrict__ kf,
    const f16* __restrict__ vf, float* __restrict__ out) {
  __shared__ __align__(16) f16 q_lds[16384];      // 32 frag blocks x 512 f16 = 32 KB
  __shared__ __align__(16) f16 sP2[4096];         // 8 chunks x 64 lanes x 8 f16
  __shared__ __align__(16) float s_pmax[128];
  __shared__ __align__(16) float s_psum[128];

  const int tid = threadIdx.x;
  const int lane = tid & 63, wvx = tid >> 6;
  const int l31 = lane & 31, lh = lane >> 5;
  const int bid = blockIdx.x;
  const int b = bid & 7;
  const int i0 = (bid >> 3) * 32;

  const f16* kfw = kf + (size_t)(b * 72 + wvx) * 16384 + lane * 8;
  const f16* vfw = vf + (size_t)(b * 16 + wvx * 4) * 73728 + lane * 8;

  // ---- stage q tile (32 x 512) once, into frag-block layout ----
  {
    const f16* qb = qt + ((size_t)b * NN + i0) * NE;
#pragma unroll
    for (int it = 0; it < 8; ++it) {
      int g = it * 256 + tid;
      int row = g >> 6, gr = g & 63;
      f16x8 v = *(const f16x8*)(qb + row * NE + gr * 8);
      // frag block ec=gr>>1: lane' = (gr&1)*32 + row, inner = e&7
      *(f16x8*)(q_lds + (gr >> 1) * 512 + (gr & 1) * 256 + row * 8) = v;
    }
  }
  // prologue: k(0)[0..11] — overlaps staging; lands at the staging barrier
  f16x8 kpipe[12];
#pragma unroll
  for (int t = 0; t < 12; ++t) kpipe[t] = *(const f16x8*)(kfw + t * 512);
  __syncthreads();

  float m_reg = -1e30f, l_reg = 0.f;
  f32x16 O[4];
#pragma unroll
  for (int nt = 0; nt < 4; ++nt)
#pragma unroll
    for (int i = 0; i < 16; ++i) O[nt][i] = 0.f;

  const f16* qlw = q_lds + lane * 8;
  f16x8 vpipe[12];

  for (int jt = 0; jt < 18; ++jt) {
    const f16* kfl = kfw + (size_t)jt * 4 * 16384;
    const f16* vfl = vfw + (size_t)jt * 8 * 512;

    // ---- Phase A: S = k.q^T, depth-12 k stream (12 pre-landed) ----
    f32x16 S0, S1;
#pragma unroll
    for (int i = 0; i < 16; ++i) { S0[i] = 0.f; S1[i] = 0.f; }
#pragma unroll
    for (int c = 0; c < 32; ++c) {
      f16x8 ak = kpipe[c % 12];
      if (c + 12 < 32) kpipe[c % 12] = *(const f16x8*)(kfl + (c + 12) * 512);
      f16x8 aq = *(const f16x8*)(qlw + c * 512);
      if (c & 1) S1 = mfma16(ak, aq, S1);
      else       S0 = mfma16(ak, aq, S0);
    }
    // early v(jt)[0..11] issue — drains under softmax + barriers
#pragma unroll
    for (int t = 0; t < 12; ++t) {
      int nt = t & 3, cg = t >> 2;
      vpipe[t] = *(const f16x8*)(vfl + (size_t)nt * 73728 + cg * 512);
    }
    f32x16 S;
#pragma unroll
    for (int r = 0; r < 16; ++r) S[r] = S0[r] + S1[r];

    // ---- Phase B: lane-local softmax, 2 barriers ----
    float wmax = S[0];
#pragma unroll
    for (int r = 1; r < 16; ++r) wmax = fmaxf(wmax, S[r]);
    wmax = fmaxf(wmax, __shfl_xor(wmax, 32, 64));
    if (lane < 32) s_pmax[l31 * 4 + wvx] = wmax;
    __syncthreads();                              // barrier 1 (also fences sP2)
    f32x4 pm4 = *(const f32x4*)(s_pmax + l31 * 4);
    float gmax = fmaxf(fmaxf(pm4[0], pm4[1]), fmaxf(pm4[2], pm4[3]));
    float mnew = fmaxf(m_reg, gmax);
    float alpha = __expf(m_reg - mnew);
    m_reg = mnew;

    f16 ph[16];
    float psum = 0.f;
#pragma unroll
    for (int r = 0; r < 16; ++r) {
      f16 p = (f16)__expf(S[r] - mnew);
      ph[r] = p;
      psum += (float)p;
    }
    // pack quads -> B-frags via cross-half exchange, write sP2
    union Q4 { f16x4 h; int i2[2]; };
    Q4 q4[4];
#pragma unroll
    for (int t = 0; t < 4; ++t)
#pragma unroll
      for (int u = 0; u < 4; ++u) q4[t].h[u] = ph[t * 4 + u];
#pragma unroll
    for (int ks = 0; ks < 2; ++ks) {
      Q4 t1, t2;
      t1.i2[0] = __shfl_xor(q4[2 * ks + 1].i2[0], 32, 64);
      t1.i2[1] = __shfl_xor(q4[2 * ks + 1].i2[1], 32, 64);
      t2.i2[0] = __shfl_xor(q4[2 * ks].i2[0], 32, 64);
      t2.i2[1] = __shfl_xor(q4[2 * ks].i2[1], 32, 64);
      f16x4 first  = lh ? t1.h : q4[2 * ks].h;
      f16x4 second = lh ? q4[2 * ks + 1].h : t2.h;
      f16x8 frag;
#pragma unroll
      for (int u = 0; u < 4; ++u) { frag[u] = first[u]; frag[4 + u] = second[u]; }
      *(f16x8*)(sP2 + ((wvx * 2 + ks) * 64 + lane) * 8) = frag;
    }
    psum += __shfl_xor(psum, 32, 64);
    if (lane < 32) s_psum[l31 * 4 + wvx] = psum;
    // rescale O while the exchange settles
#pragma unroll
    for (int nt = 0; nt < 4; ++nt)
#pragma unroll
      for (int r = 0; r < 16; ++r) O[nt][r] *= alpha;
    __syncthreads();                              // barrier 2 (P + sums visible)
    f32x4 ps4 = *(const f32x4*)(s_psum + l31 * 4);
    l_reg = l_reg * alpha + (ps4[0] + ps4[1] + ps4[2] + ps4[3]);

    // ---- Phase C: O += V.P — k(jt+1)[0..11] issued first (no barrier to A) ----
    if (jt < 17) {
      const f16* kn = kfw + (size_t)(jt + 1) * 4 * 16384;
#pragma unroll
      for (int t = 0; t < 12; ++t) kpipe[t] = *(const f16x8*)(kn + t * 512);
    }
    f16x8 apc = *(const f16x8*)(sP2 + (0 * 64 + lane) * 8);
    f16x8 apn = *(const f16x8*)(sP2 + (1 * 64 + lane) * 8);
#pragma unroll
    for (int c = 0; c < 32; ++c) {
      int nt = c & 3, cg = c >> 2;
      f16x8 av = vpipe[c % 12];
      if (c + 12 < 32) {
        int c2 = c + 12, nt2 = c2 & 3, cg2 = c2 >> 2;
        vpipe[c % 12] = *(const f16x8*)(vfl + (size_t)nt2 * 73728 + cg2 * 512);
      }
      O[nt] = mfma16(av, apc, O[nt]);
      if (nt == 3) {
        apc = apn;
        if (cg + 2 < 8) apn = *(const f16x8*)(sP2 + ((cg + 2) * 64 + lane) * 8);
      }
    }
  }

  // ---- epilogue: per-lane normalize + v residual, direct coalesced stores ----
  float inv = 1.0f / l_reg;
  const int ii = i0 + l31;
  const int jcR = ii >> 4, lhR = (ii >> 3) & 1, uR = ii & 7;
#pragma unroll
  for (int nt = 0; nt < 4; ++nt) {
    const f16* vres = vf + ((((size_t)(b * 16 + wvx * 4 + nt)) * 144 + jcR) * 64 + lhR * 32) * 8 + uR;
    const int ebase = wvx * 128 + nt * 32;
#pragma unroll
    for (int r = 0; r < 16; ++r) {
      int el = (r & 3) + 8 * (r >> 2) + 4 * lh;
      float rv = (float)vres[el * 8];
      out[((size_t)b * NE + ebase + el) * NN + ii] = O[nt][r] * inv + rv;
    }
  }
}

// ---------------- launch ----------------
extern "C" void kernel_launch(void* const* d_in, const int* in_sizes, int n_in,
                              void* d_out, int out_size, void* d_ws, size_t ws_size,
                              hipStream_t stream) {
  const float* feat = (const float*)d_in[0];
  const float* Wq = (const float*)d_in[1];
  const float* bq = (const float*)d_in[2];
  const float* Wk = (const float*)d_in[3];
  const float* bk = (const float*)d_in[4];
  const float* Wv = (const float*)d_in[5];
  const float* bv = (const float*)d_in[6];
  float* out = (float*)d_out;

  char* ws = (char*)d_ws;
  size_t off = 0;
  auto alloc = [&](size_t bytes) {
    void* p = ws + off;
    off += (bytes + 255) & ~(size_t)255;
    return p;
  };
  const size_t FP = (size_t)NB * HP * HP * NC;     // 5,120,000
  const size_t WP = (size_t)9 * NE * NC;           // 1,179,648
  const size_t QP = (size_t)NB * NN * NE;          // 9,437,184
  f16* fp  = (f16*)alloc(FP * 2);
  f16* wq  = (f16*)alloc(WP * 2);
  f16* wk  = (f16*)alloc(WP * 2);
  f16* wv  = (f16*)alloc(WP * 2);
  f16* q_t = (f16*)alloc(QP * 2);
  f16* k_f = (f16*)alloc(QP * 2);
  f16* v_f = (f16*)alloc(QP * 2);

  pack_feat<<<dim3(NB, HP), dim3(256), 0, stream>>>(feat, fp);
  pack_w<<<dim3(WP / 256), dim3(256), 0, stream>>>(Wq, Wk, Wv, wq, wk, wv);

  conv3_all<<<dim3(16, 48, 3), dim3(256), 0, stream>>>(
      fp, wq, wk, wv, bq, bk, bv, q_t, k_f, v_f);

  attn<<<dim3(576), dim3(256), 0, stream>>>(q_t, k_f, v_f, out);
}